// Round 1
// baseline (797.155 us; speedup 1.0000x reference)
//
#include <hip/hip_runtime.h>
#include <hip/hip_bf16.h>
#include <math.h>

// Problem constants (B,T,D,N from the reference)
#define BB 4
#define TT 1024
#define DD 1024
#define NNs 16
#define MM (BB*TT)          // 4096 rows
#define CHUNK 64
#define NCHUNK (TT/CHUNK)   // 16

__device__ __forceinline__ float silu_f(float v)     { return v / (1.f + expf(-v)); }
__device__ __forceinline__ float softplus_f(float v) { return fmaxf(v, 0.f) + log1pf(expf(-fabsf(v))); }

// ---------------------------------------------------------------------------
// GEMM: C[M,Nn] = A[M,K] @ W[K,Nn] + bias ; EPI: 0=none, 1=silu, 2=softplus
// 128x128 block tile, BK=16, 256 threads, 8x8 micro-tile. fp32 vector-ALU.
// ---------------------------------------------------------------------------
template<int EPI>
__global__ __launch_bounds__(256) void gemm_f32(
    const float* __restrict__ A, const float* __restrict__ W,
    const float* __restrict__ bias, float* __restrict__ C,
    int M, int Nn, int K)
{
  __shared__ float As[16][132];   // [k][m], +4 pad (row = 528B, 16B-aligned)
  __shared__ float Ws[16][132];   // [k][n]

  const int tid = threadIdx.x;
  const int bm0 = blockIdx.y * 128;
  const int bn0 = blockIdx.x * 128;
  const int tx = tid & 15;        // n-group
  const int ty = tid >> 4;        // m-group
  const int ar = tid >> 2;        // 0..63 (A row within tile)
  const int ak = (tid & 3) << 2;  // 0,4,8,12 (A k within tile)
  const int wk = tid >> 5;        // 0..7  (W k within tile)
  const int wn = (tid & 31) << 2; // 0..124 (W n within tile)

  const float* Ap0 = A + (size_t)(bm0 + ar) * K + ak;
  const float* Ap1 = Ap0 + (size_t)64 * K;
  const float* Wp0 = W + (size_t)wk * Nn + bn0 + wn;
  const float* Wp1 = Wp0 + (size_t)8 * Nn;

  float acc[8][8];
  #pragma unroll
  for (int i = 0; i < 8; i++)
    #pragma unroll
    for (int j = 0; j < 8; j++) acc[i][j] = 0.f;

  for (int k0 = 0; k0 < K; k0 += 16) {
    float4 a0 = *(const float4*)(Ap0 + k0);
    float4 a1 = *(const float4*)(Ap1 + k0);
    float4 w0 = *(const float4*)(Wp0 + (size_t)k0 * Nn);
    float4 w1 = *(const float4*)(Wp1 + (size_t)k0 * Nn);
    __syncthreads();  // previous iteration's readers done before overwrite
    As[ak+0][ar] = a0.x; As[ak+1][ar] = a0.y; As[ak+2][ar] = a0.z; As[ak+3][ar] = a0.w;
    As[ak+0][ar+64] = a1.x; As[ak+1][ar+64] = a1.y; As[ak+2][ar+64] = a1.z; As[ak+3][ar+64] = a1.w;
    *(float4*)&Ws[wk  ][wn] = w0;
    *(float4*)&Ws[wk+8][wn] = w1;
    __syncthreads();
    #pragma unroll
    for (int kk = 0; kk < 16; kk++) {
      float4 aA = *(const float4*)&As[kk][ty*8];
      float4 aB = *(const float4*)&As[kk][ty*8+4];
      float4 bA = *(const float4*)&Ws[kk][tx*8];
      float4 bB = *(const float4*)&Ws[kk][tx*8+4];
      float av[8] = {aA.x,aA.y,aA.z,aA.w,aB.x,aB.y,aB.z,aB.w};
      float bv[8] = {bA.x,bA.y,bA.z,bA.w,bB.x,bB.y,bB.z,bB.w};
      #pragma unroll
      for (int i = 0; i < 8; i++)
        #pragma unroll
        for (int j = 0; j < 8; j++)
          acc[i][j] = fmaf(av[i], bv[j], acc[i][j]);
    }
  }

  float bv[8];
  #pragma unroll
  for (int j = 0; j < 8; j++) bv[j] = bias[bn0 + tx*8 + j];
  #pragma unroll
  for (int i = 0; i < 8; i++) {
    float o[8];
    #pragma unroll
    for (int j = 0; j < 8; j++) {
      float v = acc[i][j] + bv[j];
      if (EPI == 1) v = silu_f(v);
      else if (EPI == 2) v = softplus_f(v);
      o[j] = v;
    }
    float* Crow = C + (size_t)(bm0 + ty*8 + i) * Nn + bn0 + tx*8;
    *(float4*)(Crow)     = make_float4(o[0], o[1], o[2], o[3]);
    *(float4*)(Crow + 4) = make_float4(o[4], o[5], o[6], o[7]);
  }
}

// ---------------------------------------------------------------------------
// Depthwise conv3 (same padding over T) + silu.  x1[B,T,D] -> x[B,T,D]
// ---------------------------------------------------------------------------
__global__ __launch_bounds__(256) void conv_silu(
    const float* __restrict__ x1, const float* __restrict__ cw,
    const float* __restrict__ cb, float* __restrict__ x)
{
  int idx = blockIdx.x * 256 + threadIdx.x;       // over MM*DD/4
  int d4 = idx & (DD/4 - 1);
  int bt = idx >> 8;                              // DD/4 == 256
  int t  = bt & (TT - 1);
  const float4* b4 = (const float4*)x1;
  size_t ri = (size_t)bt * (DD/4) + d4;
  float4 zz = make_float4(0.f, 0.f, 0.f, 0.f);
  float4 vc = b4[ri];
  float4 vm = (t > 0)      ? b4[ri - DD/4] : zz;
  float4 vp = (t < TT - 1) ? b4[ri + DD/4] : zz;
  float rm[4] = {vm.x, vm.y, vm.z, vm.w};
  float rc[4] = {vc.x, vc.y, vc.z, vc.w};
  float rp[4] = {vp.x, vp.y, vp.z, vp.w};
  float o[4];
  #pragma unroll
  for (int j = 0; j < 4; j++) {
    int d = d4*4 + j;
    float v = rm[j]*cw[d*3+0] + rc[j]*cw[d*3+1] + rp[j]*cw[d*3+2] + cb[d];
    o[j] = silu_f(v);
  }
  ((float4*)x)[ri] = make_float4(o[0], o[1], o[2], o[3]);
}

// ---------------------------------------------------------------------------
// B/C projections: Bm[M,N] = x@Wb + bb ; Cm[M,N] = x@Wc + bc   (N=16)
// Block = 256 threads handles 8 rows; x rows staged in LDS.
// ---------------------------------------------------------------------------
__global__ __launch_bounds__(256) void proj_bc(
    const float* __restrict__ x,
    const float* __restrict__ Wb, const float* __restrict__ bb,
    const float* __restrict__ Wc, const float* __restrict__ bc,
    float* __restrict__ Bm, float* __restrict__ Cm)
{
  __shared__ float xs[8][DD];
  int row0 = blockIdx.x * 8;
  for (int i = threadIdx.x; i < 8 * DD/4; i += 256) {
    int r = i >> 8; int c4 = i & 255;
    *(float4*)&xs[r][c4*4] = *(const float4*)(x + (size_t)(row0 + r)*DD + c4*4);
  }
  __syncthreads();
  int r  = threadIdx.x >> 5;       // 0..7
  int n  = threadIdx.x & 31;       // 0..31 ; <16 -> Bm, >=16 -> Cm
  int nn = n & 15;
  const float* W = (n < 16) ? Wb : Wc;
  float acc = 0.f;
  #pragma unroll 4
  for (int k = 0; k < DD; k++) acc = fmaf(xs[r][k], W[k*NNs + nn], acc);
  acc += (n < 16) ? bb[nn] : bc[nn];
  float* dst = (n < 16) ? Bm : Cm;
  dst[(size_t)(row0 + r)*NNs + nn] = acc;
}

// ---------------------------------------------------------------------------
// Selective scan, 3-phase chunked (C=16 chunks of L=64).
// Phase 1: per-chunk local scan with h0=0 -> P (decay product), S (local final)
// ---------------------------------------------------------------------------
__global__ __launch_bounds__(256) void scan_local(
    const float* __restrict__ dt, const float* __restrict__ x,
    const float* __restrict__ Bm, const float* __restrict__ A,
    float* __restrict__ P, float* __restrict__ S)
{
  __shared__ float Bs[CHUNK*NNs];
  int bid = blockIdx.x;                 // B*NCHUNK*(DD/256) = 256 blocks
  int dblk = bid & 3;
  int c = (bid >> 2) & 15;
  int b = bid >> 6;
  int d = dblk*256 + threadIdx.x;
  int t0 = c * CHUNK;
  for (int i = threadIdx.x; i < CHUNK*NNs; i += 256)
    Bs[i] = Bm[(size_t)(b*TT + t0)*NNs + i];
  float a[NNs];
  #pragma unroll
  for (int n = 0; n < NNs; n++) a[n] = A[d*NNs + n];
  __syncthreads();
  float h[NNs], p[NNs];
  #pragma unroll
  for (int n = 0; n < NNs; n++) { h[n] = 0.f; p[n] = 1.f; }
  size_t base = (size_t)(b*TT + t0)*DD + d;
  for (int tt = 0; tt < CHUNK; tt++) {
    float dtv = dt[base + (size_t)tt*DD];
    float xv  = x [base + (size_t)tt*DD];
    float dx = dtv * xv;
    #pragma unroll
    for (int n = 0; n < NNs; n++) {
      float e = __expf(dtv * a[n]);
      h[n] = fmaf(e, h[n], dx * Bs[tt*NNs + n]);
      p[n] *= e;
    }
  }
  size_t o = ((size_t)((b*NCHUNK + c)*DD + d)) * NNs;
  #pragma unroll
  for (int n = 0; n < NNs; n += 4) {
    *(float4*)&P[o+n] = make_float4(p[n], p[n+1], p[n+2], p[n+3]);
    *(float4*)&S[o+n] = make_float4(h[n], h[n+1], h[n+2], h[n+3]);
  }
}

// Phase 2: sequential combine over chunks -> per-chunk entering state H0
__global__ __launch_bounds__(256) void scan_combine(
    const float* __restrict__ P, const float* __restrict__ S,
    float* __restrict__ H0)
{
  int g = blockIdx.x*256 + threadIdx.x;   // over B*DD*NNs = 65536
  int n = g & 15; int d = (g >> 4) & 1023; int b = g >> 14;
  float h = 0.f;
  for (int c = 0; c < NCHUNK; c++) {
    size_t idx = ((size_t)((b*NCHUNK + c)*DD + d)) * NNs + n;
    H0[idx] = h;
    h = fmaf(P[idx], h, S[idx]);
  }
}

// Phase 3: replay local scan with correct h0, produce y, fuse gate: xs = y*z
__global__ __launch_bounds__(256) void scan_y(
    const float* __restrict__ dt, const float* __restrict__ x,
    const float* __restrict__ Bm, const float* __restrict__ Cm,
    const float* __restrict__ A,  const float* __restrict__ H0,
    const float* __restrict__ z,  float* __restrict__ xs)
{
  __shared__ float Bs[CHUNK*NNs];
  __shared__ float Cs[CHUNK*NNs];
  int bid = blockIdx.x;
  int dblk = bid & 3;
  int c = (bid >> 2) & 15;
  int b = bid >> 6;
  int d = dblk*256 + threadIdx.x;
  int t0 = c * CHUNK;
  for (int i = threadIdx.x; i < CHUNK*NNs; i += 256) {
    Bs[i] = Bm[(size_t)(b*TT + t0)*NNs + i];
    Cs[i] = Cm[(size_t)(b*TT + t0)*NNs + i];
  }
  float a[NNs];
  #pragma unroll
  for (int n = 0; n < NNs; n++) a[n] = A[d*NNs + n];
  size_t ho = ((size_t)((b*NCHUNK + c)*DD + d)) * NNs;
  float h[NNs];
  #pragma unroll
  for (int n = 0; n < NNs; n += 4) {
    float4 h4 = *(const float4*)&H0[ho+n];
    h[n] = h4.x; h[n+1] = h4.y; h[n+2] = h4.z; h[n+3] = h4.w;
  }
  __syncthreads();
  size_t base = (size_t)(b*TT + t0)*DD + d;
  for (int tt = 0; tt < CHUNK; tt++) {
    float dtv = dt[base + (size_t)tt*DD];
    float xv  = x [base + (size_t)tt*DD];
    float dx = dtv * xv;
    float y = 0.f;
    #pragma unroll
    for (int n = 0; n < NNs; n++) {
      float e = __expf(dtv * a[n]);
      h[n] = fmaf(e, h[n], dx * Bs[tt*NNs + n]);
      y = fmaf(h[n], Cs[tt*NNs + n], y);
    }
    size_t gi = base + (size_t)tt*DD;
    xs[gi] = y * z[gi];
  }
}

// ---------------------------------------------------------------------------
extern "C" void kernel_launch(void* const* d_in, const int* in_sizes, int n_in,
                              void* d_out, int out_size, void* d_ws, size_t ws_size,
                              hipStream_t stream)
{
  const float* u     = (const float*)d_in[0];
  const float* Win   = (const float*)d_in[1];
  const float* b_in  = (const float*)d_in[2];
  const float* Wg    = (const float*)d_in[3];
  const float* bg    = (const float*)d_in[4];
  const float* Wout  = (const float*)d_in[5];
  const float* bout  = (const float*)d_in[6];
  const float* convw = (const float*)d_in[7];
  const float* convb = (const float*)d_in[8];
  const float* A     = (const float*)d_in[9];
  const float* Wb    = (const float*)d_in[10];
  const float* bb    = (const float*)d_in[11];
  const float* Wc    = (const float*)d_in[12];
  const float* bc    = (const float*)d_in[13];
  const float* Wdt   = (const float*)d_in[14];
  const float* bdt   = (const float*)d_in[15];
  float* out = (float*)d_out;

  // workspace layout (floats); total ~19.4M floats ~78MB
  float* ws = (float*)d_ws;
  float* x1 = ws;                       // [M,D] in_proj out; reused later as xs
  float* z  = x1 + (size_t)MM*DD;       // [M,D] gate
  float* x  = z  + (size_t)MM*DD;       // [M,D] conv+silu out
  float* dt = x  + (size_t)MM*DD;       // [M,D]
  float* Bm = dt + (size_t)MM*DD;       // [M,N]
  float* Cm = Bm + (size_t)MM*NNs;      // [M,N]
  float* P  = Cm + (size_t)MM*NNs;      // [B,C,D,N]
  float* S  = P  + (size_t)BB*NCHUNK*DD*NNs;
  float* H0 = S  + (size_t)BB*NCHUNK*DD*NNs;
  float* xs = x1;                       // reuse

  dim3 ggemm(DD/128, MM/128);           // (8, 32)

  // 1) in_proj and gate GEMMs
  gemm_f32<0><<<ggemm, 256, 0, stream>>>(u, Win, b_in, x1, MM, DD, DD);
  gemm_f32<1><<<ggemm, 256, 0, stream>>>(u, Wg,  bg,  z,  MM, DD, DD);
  // 2) depthwise conv + silu
  conv_silu<<<(MM*DD/4)/256, 256, 0, stream>>>(x1, convw, convb, x);
  // 3) dt = softplus(x@Wdt + bdt)
  gemm_f32<2><<<ggemm, 256, 0, stream>>>(x, Wdt, bdt, dt, MM, DD, DD);
  // 4) B/C projections
  proj_bc<<<MM/8, 256, 0, stream>>>(x, Wb, bb, Wc, bc, Bm, Cm);
  // 5-7) chunked selective scan (+ gate fused in phase 3)
  scan_local  <<<BB*NCHUNK*(DD/256), 256, 0, stream>>>(dt, x, Bm, A, P, S);
  scan_combine<<<(BB*DD*NNs)/256,    256, 0, stream>>>(P, S, H0);
  scan_y      <<<BB*NCHUNK*(DD/256), 256, 0, stream>>>(dt, x, Bm, Cm, A, H0, z, xs);
  // 8) out = xs @ Wout + bout
  gemm_f32<0><<<ggemm, 256, 0, stream>>>(xs, Wout, bout, out, MM, DD, DD);
}

// Round 3
// 379.669 us; speedup vs baseline: 2.0996x; 2.0996x over previous
//
#include <hip/hip_runtime.h>
#include <hip/hip_bf16.h>
#include <math.h>

// Problem constants (B,T,D,N from the reference)
#define BB 4
#define TT 1024
#define DD 1024
#define NNs 16
#define MM (BB*TT)          // 4096 rows
#define MMDD ((size_t)MM*DD)
#define CHUNK 64
#define NCHUNK (TT/CHUNK)   // 16

typedef short bf16x8 __attribute__((ext_vector_type(8)));
typedef float f32x4  __attribute__((ext_vector_type(4)));

__device__ __forceinline__ float silu_f(float v)     { return v / (1.f + __expf(-v)); }
__device__ __forceinline__ float softplus_f(float v) { return fmaxf(v, 0.f) + log1pf(__expf(-fabsf(v))); }

// fp32 -> bf16 (RNE) as raw bits
__device__ __forceinline__ unsigned short f2bf(float f) {
  unsigned u = __builtin_bit_cast(unsigned, f);
  u += 0x7fffu + ((u >> 16) & 1u);
  return (unsigned short)(u >> 16);
}
__device__ __forceinline__ unsigned pk2(float a, float b) {
  return (unsigned)f2bf(a) | ((unsigned)f2bf(b) << 16);
}

// async global->LDS, 16B per lane; lds ptr must be wave-uniform
__device__ __forceinline__ void gload16(const void* g, void* l) {
  __builtin_amdgcn_global_load_lds(
      (const __attribute__((address_space(1))) unsigned*)g,
      (__attribute__((address_space(3))) unsigned*)l, 16, 0, 0);
}

// ---------------------------------------------------------------------------
// Weight convert+transpose: W[K][N] f32 -> Wt[N][K] bf16   (K=N=DD)
// ---------------------------------------------------------------------------
__global__ __launch_bounds__(256) void wconv_t(
    const float* __restrict__ W, short* __restrict__ Wt)
{
  __shared__ float t[32][33];
  int n0 = blockIdx.x * 32, k0 = blockIdx.y * 32;
  int r  = threadIdx.x >> 3;
  int c4 = (threadIdx.x & 7) * 4;
  float4 v = *(const float4*)(W + (size_t)(k0 + r) * DD + n0 + c4);
  t[r][c4+0] = v.x; t[r][c4+1] = v.y; t[r][c4+2] = v.z; t[r][c4+3] = v.w;
  __syncthreads();
  short o0 = (short)f2bf(t[c4+0][r]);
  short o1 = (short)f2bf(t[c4+1][r]);
  short o2 = (short)f2bf(t[c4+2][r]);
  short o3 = (short)f2bf(t[c4+3][r]);
  *(short4*)(Wt + (size_t)(n0 + r) * DD + k0 + c4) = make_short4(o0, o1, o2, o3);
}

// fp32 -> bf16 bulk convert (8 elems/thread)
__global__ __launch_bounds__(256) void to_bf16(
    const float* __restrict__ in, short* __restrict__ out)
{
  size_t i = (size_t)(blockIdx.x * 256 + threadIdx.x) * 8;
  float4 a = *(const float4*)(in + i);
  float4 b = *(const float4*)(in + i + 4);
  *(uint4*)(out + i) = make_uint4(pk2(a.x,a.y), pk2(a.z,a.w),
                                  pk2(b.x,b.y), pk2(b.z,b.w));
}

// ---------------------------------------------------------------------------
// bf16 MFMA GEMM core (m97 structure): C[M][Nn] = Ab[M][K] @ Bt[Nn][K]^T + bias
// 128x128 tile, BK=64, 256 threads, wave -> 64x64 (4x4 frags of 16x16x32).
// epi: 0=none, 1=silu, 2=softplus
// ---------------------------------------------------------------------------
__device__ __forceinline__ void gemm_core(
    const short* __restrict__ Ab, const short* __restrict__ Bt,
    const float* __restrict__ bias, float* __restrict__ C,
    int Nn, int K, int bm0, int bn0, int epi,
    short* As, short* Bs)
{
  const int tid  = threadIdx.x;
  const int lane = tid & 63;
  const int w    = tid >> 6;          // wave 0..3
  const int wm0  = (w >> 1) * 64;
  const int wn0  = (w & 1) * 64;

  const int srow = tid >> 3;          // 0..31 (staging row)
  const int scol = (tid & 7) * 8;     // staging k-offset (elems)

  const short* gA = Ab + (size_t)(bm0 + srow) * K + scol;
  const short* gB = Bt + (size_t)(bn0 + srow) * K + scol;
  char* ldsA = (char*)As;
  char* ldsB = (char*)Bs;
  const int wuni = w * 1024;          // wave-uniform LDS byte offset

  f32x4 acc[4][4];
  const f32x4 zz = {0.f, 0.f, 0.f, 0.f};
  #pragma unroll
  for (int m = 0; m < 4; m++)
    #pragma unroll
    for (int n = 0; n < 4; n++) acc[m][n] = zz;

  const int fr = lane & 15;           // frag row (A) / col (B)
  const int ks = (lane >> 4) * 8;     // frag k-offset within 32-slice

  for (int k0 = 0; k0 < K; k0 += 64) {
    __syncthreads();                  // prev readers done
    #pragma unroll
    for (int i = 0; i < 4; i++) {
      gload16(gA + (size_t)(i * 32) * K + k0, ldsA + i * 4096 + wuni);
      gload16(gB + (size_t)(i * 32) * K + k0, ldsB + i * 4096 + wuni);
    }
    __syncthreads();                  // vmcnt(0) drain + barrier
    #pragma unroll
    for (int s = 0; s < 2; s++) {
      bf16x8 af[4], bf[4];
      #pragma unroll
      for (int m = 0; m < 4; m++)
        af[m] = *(const bf16x8*)&As[(wm0 + m*16 + fr) * 64 + s*32 + ks];
      #pragma unroll
      for (int n = 0; n < 4; n++)
        bf[n] = *(const bf16x8*)&Bs[(wn0 + n*16 + fr) * 64 + s*32 + ks];
      #pragma unroll
      for (int m = 0; m < 4; m++)
        #pragma unroll
        for (int n = 0; n < 4; n++)
          acc[m][n] = __builtin_amdgcn_mfma_f32_16x16x32_bf16(af[m], bf[n], acc[m][n], 0, 0, 0);
    }
  }

  // epilogue: C/D layout col = lane&15, row = (lane>>4)*4 + reg
  const int orow = (lane >> 4) * 4;
  const int ocol = lane & 15;
  #pragma unroll
  for (int n = 0; n < 4; n++) {
    const int col = bn0 + wn0 + n*16 + ocol;
    const float bv = bias[col];
    #pragma unroll
    for (int m = 0; m < 4; m++) {
      #pragma unroll
      for (int r = 0; r < 4; r++) {
        float v = acc[m][n][r] + bv;
        if (epi == 1) v = silu_f(v);
        else if (epi == 2) v = softplus_f(v);
        C[(size_t)(bm0 + wm0 + m*16 + orow + r) * Nn + col] = v;
      }
    }
  }
}

__global__ __launch_bounds__(256) void gemm_bf16_k(
    const short* __restrict__ Ab, const short* __restrict__ Bt,
    const float* __restrict__ bias, float* __restrict__ C,
    int Nn, int K, int epi)
{
  __shared__ short As[128*64];
  __shared__ short Bs[128*64];
  gemm_core(Ab, Bt, bias, C, Nn, K, blockIdx.y * 128, blockIdx.x * 128, epi, As, Bs);
}

// fused in_proj + gate: grid.x = 16 (first 8 -> x1/no-act, last 8 -> z/silu)
__global__ __launch_bounds__(256) void gemm_ing_k(
    const short* __restrict__ ub,
    const short* __restrict__ Wti, const short* __restrict__ Wtg,
    const float* __restrict__ b_in, const float* __restrict__ bg,
    float* __restrict__ x1, float* __restrict__ z)
{
  __shared__ short As[128*64];
  __shared__ short Bs[128*64];
  const int gate = (int)(blockIdx.x >> 3);
  gemm_core(ub, gate ? Wtg : Wti, gate ? bg : b_in, gate ? z : x1,
            DD, DD, blockIdx.y * 128, (blockIdx.x & 7) * 128, gate ? 1 : 0, As, Bs);
}

// ---------------------------------------------------------------------------
// Depthwise conv3 (same over T) + silu. Writes fp32 x and bf16 xb.
// ---------------------------------------------------------------------------
__global__ __launch_bounds__(256) void conv_silu(
    const float* __restrict__ x1, const float* __restrict__ cw,
    const float* __restrict__ cb, float* __restrict__ x,
    short* __restrict__ xb)
{
  int idx = blockIdx.x * 256 + threadIdx.x;       // over MM*DD/4
  int d4 = idx & (DD/4 - 1);
  int bt = idx >> 8;                              // DD/4 == 256
  int t  = bt & (TT - 1);
  const float4* b4 = (const float4*)x1;
  size_t ri = (size_t)bt * (DD/4) + d4;
  float4 zz = make_float4(0.f, 0.f, 0.f, 0.f);
  float4 vc = b4[ri];
  float4 vm = (t > 0)      ? b4[ri - DD/4] : zz;
  float4 vp = (t < TT - 1) ? b4[ri + DD/4] : zz;
  float rm[4] = {vm.x, vm.y, vm.z, vm.w};
  float rc[4] = {vc.x, vc.y, vc.z, vc.w};
  float rp[4] = {vp.x, vp.y, vp.z, vp.w};
  float o[4];
  #pragma unroll
  for (int j = 0; j < 4; j++) {
    int d = d4*4 + j;
    float v = rm[j]*cw[d*3+0] + rc[j]*cw[d*3+1] + rp[j]*cw[d*3+2] + cb[d];
    o[j] = silu_f(v);
  }
  ((float4*)x)[ri] = make_float4(o[0], o[1], o[2], o[3]);
  ((uint2*)xb)[ri] = make_uint2(pk2(o[0], o[1]), pk2(o[2], o[3]));
}

// ---------------------------------------------------------------------------
// B/C projections (N=16 each): Bm = x@Wb + bb ; Cm = x@Wc + bc
// ---------------------------------------------------------------------------
__global__ __launch_bounds__(256) void proj_bc(
    const float* __restrict__ x,
    const float* __restrict__ Wb, const float* __restrict__ bb,
    const float* __restrict__ Wc, const float* __restrict__ bc,
    float* __restrict__ Bm, float* __restrict__ Cm)
{
  __shared__ float xs[8][DD];
  int row0 = blockIdx.x * 8;
  for (int i = threadIdx.x; i < 8 * DD/4; i += 256) {
    int r = i >> 8; int c4 = i & 255;
    *(float4*)&xs[r][c4*4] = *(const float4*)(x + (size_t)(row0 + r)*DD + c4*4);
  }
  __syncthreads();
  int r  = threadIdx.x >> 5;
  int n  = threadIdx.x & 31;
  int nn = n & 15;
  const float* W = (n < 16) ? Wb : Wc;
  float acc = 0.f;
  #pragma unroll 4
  for (int k = 0; k < DD; k++) acc = fmaf(xs[r][k], W[k*NNs + nn], acc);
  acc += (n < 16) ? bb[nn] : bc[nn];
  float* dst = (n < 16) ? Bm : Cm;
  dst[(size_t)(row0 + r)*NNs + nn] = acc;
}

// ---------------------------------------------------------------------------
// Selective scan, 3-phase chunked (16 chunks of 64)
// ---------------------------------------------------------------------------
__global__ __launch_bounds__(256) void scan_local(
    const float* __restrict__ dt, const float* __restrict__ x,
    const float* __restrict__ Bm, const float* __restrict__ A,
    float* __restrict__ P, float* __restrict__ S)
{
  __shared__ float Bs[CHUNK*NNs];
  int bid = blockIdx.x;
  int dblk = bid & 3;
  int c = (bid >> 2) & 15;
  int b = bid >> 6;
  int d = dblk*256 + threadIdx.x;
  int t0 = c * CHUNK;
  for (int i = threadIdx.x; i < CHUNK*NNs; i += 256)
    Bs[i] = Bm[(size_t)(b*TT + t0)*NNs + i];
  float a[NNs];
  #pragma unroll
  for (int n = 0; n < NNs; n++) a[n] = A[d*NNs + n];
  __syncthreads();
  float h[NNs], p[NNs];
  #pragma unroll
  for (int n = 0; n < NNs; n++) { h[n] = 0.f; p[n] = 1.f; }
  size_t base = (size_t)(b*TT + t0)*DD + d;
  for (int tt = 0; tt < CHUNK; tt++) {
    float dtv = dt[base + (size_t)tt*DD];
    float xv  = x [base + (size_t)tt*DD];
    float dx = dtv * xv;
    #pragma unroll
    for (int n = 0; n < NNs; n++) {
      float e = __expf(dtv * a[n]);
      h[n] = fmaf(e, h[n], dx * Bs[tt*NNs + n]);
      p[n] *= e;
    }
  }
  size_t o = ((size_t)((b*NCHUNK + c)*DD + d)) * NNs;
  #pragma unroll
  for (int n = 0; n < NNs; n += 4) {
    *(float4*)&P[o+n] = make_float4(p[n], p[n+1], p[n+2], p[n+3]);
    *(float4*)&S[o+n] = make_float4(h[n], h[n+1], h[n+2], h[n+3]);
  }
}

__global__ __launch_bounds__(256) void scan_combine(
    const float* __restrict__ P, const float* __restrict__ S,
    float* __restrict__ H0)
{
  int g = blockIdx.x*256 + threadIdx.x;   // B*DD*NNs = 65536
  int n = g & 15; int d = (g >> 4) & 1023; int b = g >> 14;
  float h = 0.f;
  for (int c = 0; c < NCHUNK; c++) {
    size_t idx = ((size_t)((b*NCHUNK + c)*DD + d)) * NNs + n;
    H0[idx] = h;
    h = fmaf(P[idx], h, S[idx]);
  }
}

// Phase 3: replay with correct h0; y = <h,C>; fuse gate; write bf16 xsb
__global__ __launch_bounds__(256) void scan_y(
    const float* __restrict__ dt, const float* __restrict__ x,
    const float* __restrict__ Bm, const float* __restrict__ Cm,
    const float* __restrict__ A,  const float* __restrict__ H0,
    const float* __restrict__ z,  short* __restrict__ xsb)
{
  __shared__ float Bs[CHUNK*NNs];
  __shared__ float Cs[CHUNK*NNs];
  int bid = blockIdx.x;
  int dblk = bid & 3;
  int c = (bid >> 2) & 15;
  int b = bid >> 6;
  int d = dblk*256 + threadIdx.x;
  int t0 = c * CHUNK;
  for (int i = threadIdx.x; i < CHUNK*NNs; i += 256) {
    Bs[i] = Bm[(size_t)(b*TT + t0)*NNs + i];
    Cs[i] = Cm[(size_t)(b*TT + t0)*NNs + i];
  }
  float a[NNs];
  #pragma unroll
  for (int n = 0; n < NNs; n++) a[n] = A[d*NNs + n];
  size_t ho = ((size_t)((b*NCHUNK + c)*DD + d)) * NNs;
  float h[NNs];
  #pragma unroll
  for (int n = 0; n < NNs; n += 4) {
    float4 h4 = *(const float4*)&H0[ho+n];
    h[n] = h4.x; h[n+1] = h4.y; h[n+2] = h4.z; h[n+3] = h4.w;
  }
  __syncthreads();
  size_t base = (size_t)(b*TT + t0)*DD + d;
  for (int tt = 0; tt < CHUNK; tt++) {
    float dtv = dt[base + (size_t)tt*DD];
    float xv  = x [base + (size_t)tt*DD];
    float dx = dtv * xv;
    float y = 0.f;
    #pragma unroll
    for (int n = 0; n < NNs; n++) {
      float e = __expf(dtv * a[n]);
      h[n] = fmaf(e, h[n], dx * Bs[tt*NNs + n]);
      y = fmaf(h[n], Cs[tt*NNs + n], y);
    }
    size_t gi = base + (size_t)tt*DD;
    xsb[gi] = (short)f2bf(y * z[gi]);
  }
}

// ---------------------------------------------------------------------------
extern "C" void kernel_launch(void* const* d_in, const int* in_sizes, int n_in,
                              void* d_out, int out_size, void* d_ws, size_t ws_size,
                              hipStream_t stream)
{
  const float* u     = (const float*)d_in[0];
  const float* Win   = (const float*)d_in[1];
  const float* b_in  = (const float*)d_in[2];
  const float* Wg    = (const float*)d_in[3];
  const float* bg    = (const float*)d_in[4];
  const float* Wout  = (const float*)d_in[5];
  const float* bout  = (const float*)d_in[6];
  const float* convw = (const float*)d_in[7];
  const float* convb = (const float*)d_in[8];
  const float* A     = (const float*)d_in[9];
  const float* Wb    = (const float*)d_in[10];
  const float* bb    = (const float*)d_in[11];
  const float* Wc    = (const float*)d_in[12];
  const float* bc    = (const float*)d_in[13];
  const float* Wdt   = (const float*)d_in[14];
  const float* bdt   = (const float*)d_in[15];
  float* out = (float*)d_out;

  // workspace layout (~88.5 MB)
  float* ws = (float*)d_ws;
  float* x1 = ws;                         // [M,D] f32 (later reused for P/S/H0)
  float* z  = x1 + MMDD;                  // [M,D] f32
  float* x  = z  + MMDD;                  // [M,D] f32
  float* dt = x  + MMDD;                  // [M,D] f32
  float* Bm = dt + MMDD;                  // [M,N]
  float* Cm = Bm + (size_t)MM*NNs;        // [M,N]
  short* ub  = (short*)(Cm + (size_t)MM*NNs);  // [M,D] bf16
  short* xb  = ub  + MMDD;                // [M,D] bf16
  short* Wti = xb  + MMDD;                // [D,D] bf16 transposed
  short* Wtg = Wti + (size_t)DD*DD;
  short* Wtd = Wtg + (size_t)DD*DD;
  short* Wto = Wtd + (size_t)DD*DD;
  float* P  = x1;                         // reuse x1 region after conv
  float* S  = P + (size_t)BB*NCHUNK*DD*NNs;
  float* H0 = S + (size_t)BB*NCHUNK*DD*NNs;
  short* xsb = ub;                        // reuse ub region after in/gate GEMM

  dim3 tgrid(DD/32, DD/32);
  wconv_t<<<tgrid, 256, 0, stream>>>(Win,  Wti);
  wconv_t<<<tgrid, 256, 0, stream>>>(Wg,   Wtg);
  wconv_t<<<tgrid, 256, 0, stream>>>(Wdt,  Wtd);
  wconv_t<<<tgrid, 256, 0, stream>>>(Wout, Wto);
  to_bf16<<<(MMDD/8)/256, 256, 0, stream>>>(u, ub);

  // 1) fused in_proj (x1) + gate (z, silu)
  gemm_ing_k<<<dim3(16, MM/128), 256, 0, stream>>>(ub, Wti, Wtg, b_in, bg, x1, z);
  // 2) depthwise conv + silu -> x (f32) + xb (bf16)
  conv_silu<<<(MMDD/4)/256, 256, 0, stream>>>(x1, convw, convb, x, xb);
  // 3) dt = softplus(x@Wdt + bdt)
  gemm_bf16_k<<<dim3(8, MM/128), 256, 0, stream>>>(xb, Wtd, bdt, dt, DD, DD, 2);
  // 4) B/C projections
  proj_bc<<<MM/8, 256, 0, stream>>>(x, Wb, bb, Wc, bc, Bm, Cm);
  // 5-7) chunked selective scan (+ gate fused in phase 3, writes bf16)
  scan_local  <<<BB*NCHUNK*(DD/256), 256, 0, stream>>>(dt, x, Bm, A, P, S);
  scan_combine<<<(BB*DD*NNs)/256,    256, 0, stream>>>(P, S, H0);
  scan_y      <<<BB*NCHUNK*(DD/256), 256, 0, stream>>>(dt, x, Bm, Cm, A, H0, z, xsb);
  // 8) out = xs @ Wout + bout
  gemm_bf16_k<<<dim3(8, MM/128), 256, 0, stream>>>(xsb, Wto, bout, out, DD, DD, 0);
}

// Round 4
// 379.173 us; speedup vs baseline: 2.1024x; 1.0013x over previous
//
#include <hip/hip_runtime.h>
#include <hip/hip_bf16.h>
#include <math.h>

// Problem constants (B,T,D,N from the reference)
#define BB 4
#define TT 1024
#define DD 1024
#define NNs 16
#define MM (BB*TT)          // 4096 rows
#define MMDD ((size_t)MM*DD)
#define CHUNK 64
#define NCHUNK (TT/CHUNK)   // 16

typedef short bf16x8 __attribute__((ext_vector_type(8)));
typedef float f32x4  __attribute__((ext_vector_type(4)));

__device__ __forceinline__ float silu_f(float v)     { return v / (1.f + __expf(-v)); }
__device__ __forceinline__ float softplus_f(float v) { return fmaxf(v, 0.f) + log1pf(__expf(-fabsf(v))); }

// fp32 -> bf16 (RNE) as raw bits
__device__ __forceinline__ unsigned short f2bf(float f) {
  unsigned u = __builtin_bit_cast(unsigned, f);
  u += 0x7fffu + ((u >> 16) & 1u);
  return (unsigned short)(u >> 16);
}
__device__ __forceinline__ unsigned pk2(float a, float b) {
  return (unsigned)f2bf(a) | ((unsigned)f2bf(b) << 16);
}

// async global->LDS, 16B per lane; lds ptr must be wave-uniform
__device__ __forceinline__ void gload16(const void* g, void* l) {
  __builtin_amdgcn_global_load_lds(
      (const __attribute__((address_space(1))) unsigned*)g,
      (__attribute__((address_space(3))) unsigned*)l, 16, 0, 0);
}

// ---------------------------------------------------------------------------
// Weight convert+transpose x4: W[K][N] f32 -> Wt[N][K] bf16 (K=N=DD), z-batched
// ---------------------------------------------------------------------------
__global__ __launch_bounds__(256) void wconv_t4(
    const float* __restrict__ W0, const float* __restrict__ W1,
    const float* __restrict__ W2, const float* __restrict__ W3,
    short* __restrict__ o0, short* __restrict__ o1,
    short* __restrict__ o2, short* __restrict__ o3)
{
  const float* W; short* Wt;
  switch (blockIdx.z) {
    case 0:  W = W0; Wt = o0; break;
    case 1:  W = W1; Wt = o1; break;
    case 2:  W = W2; Wt = o2; break;
    default: W = W3; Wt = o3; break;
  }
  __shared__ float t[32][33];
  int n0 = blockIdx.x * 32, k0 = blockIdx.y * 32;
  int r  = threadIdx.x >> 3;
  int c4 = (threadIdx.x & 7) * 4;
  float4 v = *(const float4*)(W + (size_t)(k0 + r) * DD + n0 + c4);
  t[r][c4+0] = v.x; t[r][c4+1] = v.y; t[r][c4+2] = v.z; t[r][c4+3] = v.w;
  __syncthreads();
  short q0 = (short)f2bf(t[c4+0][r]);
  short q1 = (short)f2bf(t[c4+1][r]);
  short q2 = (short)f2bf(t[c4+2][r]);
  short q3 = (short)f2bf(t[c4+3][r]);
  *(short4*)(Wt + (size_t)(n0 + r) * DD + k0 + c4) = make_short4(q0, q1, q2, q3);
}

// Wb[D][16], Wc[D][16] f32 -> Wbct[32][D] bf16 (rows 0-15 = Wb^T, 16-31 = Wc^T)
__global__ __launch_bounds__(256) void wbc_t(
    const float* __restrict__ Wb, const float* __restrict__ Wc,
    short* __restrict__ Wbct)
{
  int idx = blockIdx.x * 256 + threadIdx.x;  // 32*1024 = 32768
  int k = idx & (DD - 1);
  int n = idx >> 10;
  const float* W = (n < 16) ? Wb : Wc;
  Wbct[(size_t)n * DD + k] = (short)f2bf(W[(size_t)k * NNs + (n & 15)]);
}

// fp32 -> bf16 bulk convert (8 elems/thread)
__global__ __launch_bounds__(256) void to_bf16(
    const float* __restrict__ in, short* __restrict__ out)
{
  size_t i = (size_t)(blockIdx.x * 256 + threadIdx.x) * 8;
  float4 a = *(const float4*)(in + i);
  float4 b = *(const float4*)(in + i + 4);
  *(uint4*)(out + i) = make_uint4(pk2(a.x,a.y), pk2(a.z,a.w),
                                  pk2(b.x,b.y), pk2(b.z,b.w));
}

// ---------------------------------------------------------------------------
// bf16 MFMA GEMM core (m97 structure): C[M][Nn] = Ab[M][K] @ Bt[Nn][K]^T + bias
// 128x128 tile, BK=64, 256 threads, wave -> 64x64 (4x4 frags of 16x16x32).
// epi: 0=none, 1=silu, 2=softplus
// ---------------------------------------------------------------------------
__device__ __forceinline__ void gemm_core(
    const short* __restrict__ Ab, const short* __restrict__ Bt,
    const float* __restrict__ bias, float* __restrict__ C,
    int Nn, int K, int bm0, int bn0, int epi,
    short* As, short* Bs)
{
  const int tid  = threadIdx.x;
  const int lane = tid & 63;
  const int w    = tid >> 6;          // wave 0..3
  const int wm0  = (w >> 1) * 64;
  const int wn0  = (w & 1) * 64;

  const int srow = tid >> 3;          // 0..31 (staging row)
  const int scol = (tid & 7) * 8;     // staging k-offset (elems)

  const short* gA = Ab + (size_t)(bm0 + srow) * K + scol;
  const short* gB = Bt + (size_t)(bn0 + srow) * K + scol;
  char* ldsA = (char*)As;
  char* ldsB = (char*)Bs;
  const int wuni = w * 1024;          // wave-uniform LDS byte offset

  f32x4 acc[4][4];
  const f32x4 zz = {0.f, 0.f, 0.f, 0.f};
  #pragma unroll
  for (int m = 0; m < 4; m++)
    #pragma unroll
    for (int n = 0; n < 4; n++) acc[m][n] = zz;

  const int fr = lane & 15;           // frag row (A) / col (B)
  const int ks = (lane >> 4) * 8;     // frag k-offset within 32-slice

  for (int k0 = 0; k0 < K; k0 += 64) {
    __syncthreads();                  // prev readers done
    #pragma unroll
    for (int i = 0; i < 4; i++) {
      gload16(gA + (size_t)(i * 32) * K + k0, ldsA + i * 4096 + wuni);
      gload16(gB + (size_t)(i * 32) * K + k0, ldsB + i * 4096 + wuni);
    }
    __syncthreads();                  // vmcnt(0) drain + barrier
    #pragma unroll
    for (int s = 0; s < 2; s++) {
      bf16x8 af[4], bf[4];
      #pragma unroll
      for (int m = 0; m < 4; m++)
        af[m] = *(const bf16x8*)&As[(wm0 + m*16 + fr) * 64 + s*32 + ks];
      #pragma unroll
      for (int n = 0; n < 4; n++)
        bf[n] = *(const bf16x8*)&Bs[(wn0 + n*16 + fr) * 64 + s*32 + ks];
      #pragma unroll
      for (int m = 0; m < 4; m++)
        #pragma unroll
        for (int n = 0; n < 4; n++)
          acc[m][n] = __builtin_amdgcn_mfma_f32_16x16x32_bf16(af[m], bf[n], acc[m][n], 0, 0, 0);
    }
  }

  // epilogue: C/D layout col = lane&15, row = (lane>>4)*4 + reg
  const int orow = (lane >> 4) * 4;
  const int ocol = lane & 15;
  #pragma unroll
  for (int n = 0; n < 4; n++) {
    const int col = bn0 + wn0 + n*16 + ocol;
    const float bv = bias[col];
    #pragma unroll
    for (int m = 0; m < 4; m++) {
      #pragma unroll
      for (int r = 0; r < 4; r++) {
        float v = acc[m][n][r] + bv;
        if (epi == 1) v = silu_f(v);
        else if (epi == 2) v = softplus_f(v);
        C[(size_t)(bm0 + wm0 + m*16 + orow + r) * Nn + col] = v;
      }
    }
  }
}

__global__ __launch_bounds__(256) void gemm_bf16_k(
    const short* __restrict__ Ab, const short* __restrict__ Bt,
    const float* __restrict__ bias, float* __restrict__ C,
    int Nn, int K, int epi)
{
  __shared__ short As[128*64];
  __shared__ short Bs[128*64];
  gemm_core(Ab, Bt, bias, C, Nn, K, blockIdx.y * 128, blockIdx.x * 128, epi, As, Bs);
}

// fused in_proj + gate: grid.x = 16 (first 8 -> x1/no-act, last 8 -> z/silu)
__global__ __launch_bounds__(256) void gemm_ing_k(
    const short* __restrict__ ub,
    const short* __restrict__ Wti, const short* __restrict__ Wtg,
    const float* __restrict__ b_in, const float* __restrict__ bg,
    float* __restrict__ x1, float* __restrict__ z)
{
  __shared__ short As[128*64];
  __shared__ short Bs[128*64];
  const int gate = (int)(blockIdx.x >> 3);
  gemm_core(ub, gate ? Wtg : Wti, gate ? bg : b_in, gate ? z : x1,
            DD, DD, blockIdx.y * 128, (blockIdx.x & 7) * 128, gate ? 1 : 0, As, Bs);
}

// ---------------------------------------------------------------------------
// Fused dt GEMM + B/C projections.
// grid (9, 32): x<8 -> dt tiles (softplus); x==8 -> 128x32 B/C tile via MFMA.
// ---------------------------------------------------------------------------
__global__ __launch_bounds__(256) void gemm_dtbc_k(
    const short* __restrict__ xb, const short* __restrict__ Wtd,
    const short* __restrict__ Wbct,
    const float* __restrict__ bdt, const float* __restrict__ bb,
    const float* __restrict__ bc,
    float* __restrict__ dt, float* __restrict__ Bm, float* __restrict__ Cm)
{
  __shared__ short As[128*64];
  __shared__ short Bs[128*64];
  if (blockIdx.x < 8) {
    gemm_core(xb, Wtd, bdt, dt, DD, DD, blockIdx.y * 128, blockIdx.x * 128, 2, As, Bs);
    return;
  }
  // ---- B/C path: C'[128][32] = xb_tile @ Wbct^T ----
  const int tid  = threadIdx.x;
  const int lane = tid & 63;
  const int w    = tid >> 6;          // wave 0..3 -> 32-row band
  const int bm0  = blockIdx.y * 128;
  const int wm0  = w * 32;

  const int srow = tid >> 3;          // 0..31
  const int scol = (tid & 7) * 8;
  const short* gA = xb + (size_t)(bm0 + srow) * DD + scol;
  const short* gB = Wbct + (size_t)srow * DD + scol;   // 32 rows
  char* ldsA = (char*)As;
  char* ldsB = (char*)Bs;
  const int wuni = w * 1024;

  f32x4 acc[2][2];
  const f32x4 zz = {0.f, 0.f, 0.f, 0.f};
  #pragma unroll
  for (int m = 0; m < 2; m++)
    #pragma unroll
    for (int n = 0; n < 2; n++) acc[m][n] = zz;

  const int fr = lane & 15;
  const int ks = (lane >> 4) * 8;

  for (int k0 = 0; k0 < DD; k0 += 64) {
    __syncthreads();
    #pragma unroll
    for (int i = 0; i < 4; i++)
      gload16(gA + (size_t)(i * 32) * DD + k0, ldsA + i * 4096 + wuni);
    gload16(gB + k0, ldsB + wuni);    // 32x64 bf16 = 4KB, one round
    __syncthreads();
    #pragma unroll
    for (int s = 0; s < 2; s++) {
      bf16x8 af[2], bf[2];
      #pragma unroll
      for (int m = 0; m < 2; m++)
        af[m] = *(const bf16x8*)&As[(wm0 + m*16 + fr) * 64 + s*32 + ks];
      #pragma unroll
      for (int n = 0; n < 2; n++)
        bf[n] = *(const bf16x8*)&Bs[(n*16 + fr) * 64 + s*32 + ks];
      #pragma unroll
      for (int m = 0; m < 2; m++)
        #pragma unroll
        for (int n = 0; n < 2; n++)
          acc[m][n] = __builtin_amdgcn_mfma_f32_16x16x32_bf16(af[m], bf[n], acc[m][n], 0, 0, 0);
    }
  }

  const int orow = (lane >> 4) * 4;
  const int ocol = lane & 15;
  const float bbv = bb[ocol];
  const float bcv = bc[ocol];
  #pragma unroll
  for (int m = 0; m < 2; m++) {
    #pragma unroll
    for (int r = 0; r < 4; r++) {
      int row = bm0 + wm0 + m*16 + orow + r;
      Bm[(size_t)row * NNs + ocol] = acc[m][0][r] + bbv;
      Cm[(size_t)row * NNs + ocol] = acc[m][1][r] + bcv;
    }
  }
}

// ---------------------------------------------------------------------------
// Depthwise conv3 (same over T) + silu. Writes fp32 x and bf16 xb.
// ---------------------------------------------------------------------------
__global__ __launch_bounds__(256) void conv_silu(
    const float* __restrict__ x1, const float* __restrict__ cw,
    const float* __restrict__ cb, float* __restrict__ x,
    short* __restrict__ xb)
{
  int idx = blockIdx.x * 256 + threadIdx.x;       // over MM*DD/4
  int d4 = idx & (DD/4 - 1);
  int bt = idx >> 8;                              // DD/4 == 256
  int t  = bt & (TT - 1);
  const float4* b4 = (const float4*)x1;
  size_t ri = (size_t)bt * (DD/4) + d4;
  float4 zz = make_float4(0.f, 0.f, 0.f, 0.f);
  float4 vc = b4[ri];
  float4 vm = (t > 0)      ? b4[ri - DD/4] : zz;
  float4 vp = (t < TT - 1) ? b4[ri + DD/4] : zz;
  float rm[4] = {vm.x, vm.y, vm.z, vm.w};
  float rc[4] = {vc.x, vc.y, vc.z, vc.w};
  float rp[4] = {vp.x, vp.y, vp.z, vp.w};
  float o[4];
  #pragma unroll
  for (int j = 0; j < 4; j++) {
    int d = d4*4 + j;
    float v = rm[j]*cw[d*3+0] + rc[j]*cw[d*3+1] + rp[j]*cw[d*3+2] + cb[d];
    o[j] = silu_f(v);
  }
  ((float4*)x)[ri] = make_float4(o[0], o[1], o[2], o[3]);
  ((uint2*)xb)[ri] = make_uint2(pk2(o[0], o[1]), pk2(o[2], o[3]));
}

// ---------------------------------------------------------------------------
// Selective scan, 3-phase chunked (16 chunks of 64)
// ---------------------------------------------------------------------------
__global__ __launch_bounds__(256) void scan_local(
    const float* __restrict__ dt, const float* __restrict__ x,
    const float* __restrict__ Bm, const float* __restrict__ A,
    float* __restrict__ P, float* __restrict__ S)
{
  __shared__ float Bs[CHUNK*NNs];
  int bid = blockIdx.x;
  int dblk = bid & 3;
  int c = (bid >> 2) & 15;
  int b = bid >> 6;
  int d = dblk*256 + threadIdx.x;
  int t0 = c * CHUNK;
  for (int i = threadIdx.x; i < CHUNK*NNs; i += 256)
    Bs[i] = Bm[(size_t)(b*TT + t0)*NNs + i];
  float a[NNs];
  #pragma unroll
  for (int n = 0; n < NNs; n++) a[n] = A[d*NNs + n];
  __syncthreads();
  float h[NNs], p[NNs];
  #pragma unroll
  for (int n = 0; n < NNs; n++) { h[n] = 0.f; p[n] = 1.f; }
  size_t base = (size_t)(b*TT + t0)*DD + d;
  for (int tt = 0; tt < CHUNK; tt++) {
    float dtv = dt[base + (size_t)tt*DD];
    float xv  = x [base + (size_t)tt*DD];
    float dx = dtv * xv;
    #pragma unroll
    for (int n = 0; n < NNs; n++) {
      float e = __expf(dtv * a[n]);
      h[n] = fmaf(e, h[n], dx * Bs[tt*NNs + n]);
      p[n] *= e;
    }
  }
  size_t o = ((size_t)((b*NCHUNK + c)*DD + d)) * NNs;
  #pragma unroll
  for (int n = 0; n < NNs; n += 4) {
    *(float4*)&P[o+n] = make_float4(p[n], p[n+1], p[n+2], p[n+3]);
    *(float4*)&S[o+n] = make_float4(h[n], h[n+1], h[n+2], h[n+3]);
  }
}

__global__ __launch_bounds__(256) void scan_combine(
    const float* __restrict__ P, const float* __restrict__ S,
    float* __restrict__ H0)
{
  int g = blockIdx.x*256 + threadIdx.x;   // B*DD*NNs = 65536
  int n = g & 15; int d = (g >> 4) & 1023; int b = g >> 14;
  float h = 0.f;
  for (int c = 0; c < NCHUNK; c++) {
    size_t idx = ((size_t)((b*NCHUNK + c)*DD + d)) * NNs + n;
    H0[idx] = h;
    h = fmaf(P[idx], h, S[idx]);
  }
}

// Phase 3: replay with correct h0; y = <h,C>; fuse gate; write bf16 xsb
__global__ __launch_bounds__(256) void scan_y(
    const float* __restrict__ dt, const float* __restrict__ x,
    const float* __restrict__ Bm, const float* __restrict__ Cm,
    const float* __restrict__ A,  const float* __restrict__ H0,
    const float* __restrict__ z,  short* __restrict__ xsb)
{
  __shared__ float Bs[CHUNK*NNs];
  __shared__ float Cs[CHUNK*NNs];
  int bid = blockIdx.x;
  int dblk = bid & 3;
  int c = (bid >> 2) & 15;
  int b = bid >> 6;
  int d = dblk*256 + threadIdx.x;
  int t0 = c * CHUNK;
  for (int i = threadIdx.x; i < CHUNK*NNs; i += 256) {
    Bs[i] = Bm[(size_t)(b*TT + t0)*NNs + i];
    Cs[i] = Cm[(size_t)(b*TT + t0)*NNs + i];
  }
  float a[NNs];
  #pragma unroll
  for (int n = 0; n < NNs; n++) a[n] = A[d*NNs + n];
  size_t ho = ((size_t)((b*NCHUNK + c)*DD + d)) * NNs;
  float h[NNs];
  #pragma unroll
  for (int n = 0; n < NNs; n += 4) {
    float4 h4 = *(const float4*)&H0[ho+n];
    h[n] = h4.x; h[n+1] = h4.y; h[n+2] = h4.z; h[n+3] = h4.w;
  }
  __syncthreads();
  size_t base = (size_t)(b*TT + t0)*DD + d;
  for (int tt = 0; tt < CHUNK; tt++) {
    float dtv = dt[base + (size_t)tt*DD];
    float xv  = x [base + (size_t)tt*DD];
    float dx = dtv * xv;
    float y = 0.f;
    #pragma unroll
    for (int n = 0; n < NNs; n++) {
      float e = __expf(dtv * a[n]);
      h[n] = fmaf(e, h[n], dx * Bs[tt*NNs + n]);
      y = fmaf(h[n], Cs[tt*NNs + n], y);
    }
    size_t gi = base + (size_t)tt*DD;
    xsb[gi] = (short)f2bf(y * z[gi]);
  }
}

// ---------------------------------------------------------------------------
extern "C" void kernel_launch(void* const* d_in, const int* in_sizes, int n_in,
                              void* d_out, int out_size, void* d_ws, size_t ws_size,
                              hipStream_t stream)
{
  const float* u     = (const float*)d_in[0];
  const float* Win   = (const float*)d_in[1];
  const float* b_in  = (const float*)d_in[2];
  const float* Wg    = (const float*)d_in[3];
  const float* bg    = (const float*)d_in[4];
  const float* Wout  = (const float*)d_in[5];
  const float* bout  = (const float*)d_in[6];
  const float* convw = (const float*)d_in[7];
  const float* convb = (const float*)d_in[8];
  const float* A     = (const float*)d_in[9];
  const float* Wb    = (const float*)d_in[10];
  const float* bb    = (const float*)d_in[11];
  const float* Wc    = (const float*)d_in[12];
  const float* bc    = (const float*)d_in[13];
  const float* Wdt   = (const float*)d_in[14];
  const float* bdt   = (const float*)d_in[15];
  float* out = (float*)d_out;

  // workspace layout (~88.6 MB)
  float* ws = (float*)d_ws;
  float* x1 = ws;                         // [M,D] f32 (later reused for P/S/H0)
  float* z  = x1 + MMDD;                  // [M,D] f32
  float* x  = z  + MMDD;                  // [M,D] f32
  float* dt = x  + MMDD;                  // [M,D] f32
  float* Bm = dt + MMDD;                  // [M,N]
  float* Cm = Bm + (size_t)MM*NNs;        // [M,N]
  short* ub  = (short*)(Cm + (size_t)MM*NNs);  // [M,D] bf16
  short* xb  = ub  + MMDD;                // [M,D] bf16
  short* Wti = xb  + MMDD;                // [D,D] bf16 transposed
  short* Wtg = Wti + (size_t)DD*DD;
  short* Wtd = Wtg + (size_t)DD*DD;
  short* Wto = Wtd + (size_t)DD*DD;
  short* Wbct = Wto + (size_t)DD*DD;      // [32,D] bf16 (Wb^T | Wc^T)
  float* P  = x1;                         // reuse x1 region after conv
  float* S  = P + (size_t)BB*NCHUNK*DD*NNs;
  float* H0 = S + (size_t)BB*NCHUNK*DD*NNs;
  short* xsb = ub;                        // reuse ub region after in/gate GEMM

  // 0) weight prep (one z-batched dispatch + tiny B/C transpose) and u->bf16
  wconv_t4<<<dim3(DD/32, DD/32, 4), 256, 0, stream>>>(
      Win, Wg, Wdt, Wout, Wti, Wtg, Wtd, Wto);
  wbc_t<<<(32*DD)/256, 256, 0, stream>>>(Wb, Wc, Wbct);
  to_bf16<<<(MMDD/8)/256, 256, 0, stream>>>(u, ub);

  // 1) fused in_proj (x1) + gate (z, silu)
  gemm_ing_k<<<dim3(16, MM/128), 256, 0, stream>>>(ub, Wti, Wtg, b_in, bg, x1, z);
  // 2) depthwise conv + silu -> x (f32) + xb (bf16)
  conv_silu<<<(MMDD/4)/256, 256, 0, stream>>>(x1, convw, convb, x, xb);
  // 3) dt = softplus(x@Wdt + bdt)  AND  Bm/Cm = x@[Wb|Wc] (MFMA, fused)
  gemm_dtbc_k<<<dim3(9, MM/128), 256, 0, stream>>>(
      xb, Wtd, Wbct, bdt, bb, bc, dt, Bm, Cm);
  // 4-6) chunked selective scan (+ gate fused in phase 3, writes bf16)
  scan_local  <<<BB*NCHUNK*(DD/256), 256, 0, stream>>>(dt, x, Bm, A, P, S);
  scan_combine<<<(BB*DD*NNs)/256,    256, 0, stream>>>(P, S, H0);
  scan_y      <<<BB*NCHUNK*(DD/256), 256, 0, stream>>>(dt, x, Bm, Cm, A, H0, z, xsb);
  // 7) out = xs @ Wout + bout
  gemm_bf16_k<<<dim3(8, MM/128), 256, 0, stream>>>(xsb, Wto, bout, out, DD, DD, 0);
}

// Round 6
// 321.545 us; speedup vs baseline: 2.4791x; 1.1792x over previous
//
#include <hip/hip_runtime.h>
#include <hip/hip_bf16.h>
#include <math.h>

// Problem constants (B,T,D,N from the reference)
#define BB 4
#define TT 1024
#define DD 1024
#define NNs 16
#define MM (BB*TT)          // 4096 rows
#define MMDD ((size_t)MM*DD)
#define CHUNK 64
#define NCHUNK (TT/CHUNK)   // 16

typedef short bf16x8 __attribute__((ext_vector_type(8)));
typedef float f32x4  __attribute__((ext_vector_type(4)));

__device__ __forceinline__ float silu_f(float v)     { return v / (1.f + __expf(-v)); }
__device__ __forceinline__ float softplus_f(float v) { return fmaxf(v, 0.f) + log1pf(__expf(-fabsf(v))); }

// fp32 -> bf16 (RNE) as raw bits
__device__ __forceinline__ unsigned short f2bf(float f) {
  unsigned u = __builtin_bit_cast(unsigned, f);
  u += 0x7fffu + ((u >> 16) & 1u);
  return (unsigned short)(u >> 16);
}
__device__ __forceinline__ unsigned pk2(float a, float b) {
  return (unsigned)f2bf(a) | ((unsigned)f2bf(b) << 16);
}

// async global->LDS, 16B per lane; lds ptr must be wave-uniform
__device__ __forceinline__ void gload16(const void* g, void* l) {
  __builtin_amdgcn_global_load_lds(
      (const __attribute__((address_space(1))) unsigned*)g,
      (__attribute__((address_space(3))) unsigned*)l, 16, 0, 0);
}

// T1: bijective chunked XCD swizzle (m204). Maps HW round-robin (orig%8 -> XCD)
// so each XCD owns a CONTIGUOUS chunk of work-ids -> A-panel reuse in its L2.
__device__ __forceinline__ int2 xcd_swz(int gx) {
  int nwg  = gx * (int)gridDim.y;
  int orig = (int)blockIdx.y * gx + (int)blockIdx.x;
  int q = nwg >> 3, r = nwg & 7;
  int xcd = orig & 7, i = orig >> 3;
  int wg = (xcd < r ? xcd * (q + 1) : r * (q + 1) + (xcd - r) * q) + i;
  return make_int2(wg % gx, wg / gx);
}

// ---------------------------------------------------------------------------
// Weight convert+transpose x4: W[K][N] f32 -> Wt[N][K] bf16 (K=N=DD), z-batched
// ---------------------------------------------------------------------------
__global__ __launch_bounds__(256) void wconv_t4(
    const float* __restrict__ W0, const float* __restrict__ W1,
    const float* __restrict__ W2, const float* __restrict__ W3,
    short* __restrict__ o0, short* __restrict__ o1,
    short* __restrict__ o2, short* __restrict__ o3)
{
  const float* W; short* Wt;
  switch (blockIdx.z) {
    case 0:  W = W0; Wt = o0; break;
    case 1:  W = W1; Wt = o1; break;
    case 2:  W = W2; Wt = o2; break;
    default: W = W3; Wt = o3; break;
  }
  __shared__ float t[32][33];
  int n0 = blockIdx.x * 32, k0 = blockIdx.y * 32;
  int r  = threadIdx.x >> 3;
  int c4 = (threadIdx.x & 7) * 4;
  float4 v = *(const float4*)(W + (size_t)(k0 + r) * DD + n0 + c4);
  t[r][c4+0] = v.x; t[r][c4+1] = v.y; t[r][c4+2] = v.z; t[r][c4+3] = v.w;
  __syncthreads();
  short q0 = (short)f2bf(t[c4+0][r]);
  short q1 = (short)f2bf(t[c4+1][r]);
  short q2 = (short)f2bf(t[c4+2][r]);
  short q3 = (short)f2bf(t[c4+3][r]);
  *(short4*)(Wt + (size_t)(n0 + r) * DD + k0 + c4) = make_short4(q0, q1, q2, q3);
}

// Wb[D][16], Wc[D][16] f32 -> Wbct[32][D] bf16 (rows 0-15 = Wb^T, 16-31 = Wc^T)
__global__ __launch_bounds__(256) void wbc_t(
    const float* __restrict__ Wb, const float* __restrict__ Wc,
    short* __restrict__ Wbct)
{
  int idx = blockIdx.x * 256 + threadIdx.x;  // 32*1024 = 32768
  int k = idx & (DD - 1);
  int n = idx >> 10;
  const float* W = (n < 16) ? Wb : Wc;
  Wbct[(size_t)n * DD + k] = (short)f2bf(W[(size_t)k * NNs + (n & 15)]);
}

// fp32 -> bf16 bulk convert (8 elems/thread)
__global__ __launch_bounds__(256) void to_bf16(
    const float* __restrict__ in, short* __restrict__ out)
{
  size_t i = (size_t)(blockIdx.x * 256 + threadIdx.x) * 8;
  float4 a = *(const float4*)(in + i);
  float4 b = *(const float4*)(in + i + 4);
  *(uint4*)(out + i) = make_uint4(pk2(a.x,a.y), pk2(a.z,a.w),
                                  pk2(b.x,b.y), pk2(b.z,b.w));
}

// ---------------------------------------------------------------------------
// bf16 MFMA GEMM core, 2-phase double-buffered (T3-minimum):
// C[M][Nn] = Ab[M][K] @ Bt[Nn][K]^T + bias
// 128x128 tile, BK=64, 256 threads, wave -> 64x64 (4x4 frags of 16x16x32).
// LDS: As/Bs each 2 x (128x64) bf16 = 64KB total. One barrier per K-step;
// next tile's global_load_lds issued BEFORE current tile's MFMA so the
// barrier's implicit vmcnt(0) drains loads that overlapped compute.
// epi: 0=none, 1=silu, 2=softplus
// ---------------------------------------------------------------------------
__device__ __forceinline__ void gemm_core(
    const short* __restrict__ Ab, const short* __restrict__ Bt,
    const float* __restrict__ bias, float* __restrict__ C,
    int Nn, int K, int bm0, int bn0, int epi,
    short* As, short* Bs)
{
  const int tid  = threadIdx.x;
  const int lane = tid & 63;
  const int w    = tid >> 6;          // wave 0..3
  const int wm0  = (w >> 1) * 64;
  const int wn0  = (w & 1) * 64;

  const int srow = tid >> 3;          // 0..31 (staging row)
  const int scol = (tid & 7) * 8;     // staging k-offset (elems)

  const short* gA = Ab + (size_t)(bm0 + srow) * K + scol;
  const short* gB = Bt + (size_t)(bn0 + srow) * K + scol;
  char* ldsA = (char*)As;
  char* ldsB = (char*)Bs;
  const int wuni = w * 1024;          // wave-uniform LDS byte offset

  f32x4 acc[4][4];
  const f32x4 zz = {0.f, 0.f, 0.f, 0.f};
  #pragma unroll
  for (int m = 0; m < 4; m++)
    #pragma unroll
    for (int n = 0; n < 4; n++) acc[m][n] = zz;

  const int fr = lane & 15;           // frag row (A) / col (B)
  const int ks = (lane >> 4) * 8;     // frag k-offset within 32-slice

  const int NT = K >> 6;

  // prologue: stage tile 0 into buf 0
  #pragma unroll
  for (int i = 0; i < 4; i++) {
    gload16(gA + (size_t)(i * 32) * K, ldsA + i * 4096 + wuni);
    gload16(gB + (size_t)(i * 32) * K, ldsB + i * 4096 + wuni);
  }
  __syncthreads();                    // vmcnt(0) drain: buf0 ready

  for (int t = 0; t < NT; ++t) {
    const int cur = t & 1;
    if (t + 1 < NT) {                 // issue next tile into other buf NOW
      const int k1 = (t + 1) << 6;
      const int bo = (cur ^ 1) * 16384;
      #pragma unroll
      for (int i = 0; i < 4; i++) {
        gload16(gA + (size_t)(i * 32) * K + k1, ldsA + bo + i * 4096 + wuni);
        gload16(gB + (size_t)(i * 32) * K + k1, ldsB + bo + i * 4096 + wuni);
      }
    }
    const short* Ac = As + cur * 8192;
    const short* Bc = Bs + cur * 8192;
    #pragma unroll
    for (int s = 0; s < 2; s++) {
      bf16x8 af[4], bf[4];
      #pragma unroll
      for (int m = 0; m < 4; m++)
        af[m] = *(const bf16x8*)&Ac[(wm0 + m*16 + fr) * 64 + s*32 + ks];
      #pragma unroll
      for (int n = 0; n < 4; n++)
        bf[n] = *(const bf16x8*)&Bc[(wn0 + n*16 + fr) * 64 + s*32 + ks];
      #pragma unroll
      for (int m = 0; m < 4; m++)
        #pragma unroll
        for (int n = 0; n < 4; n++)
          acc[m][n] = __builtin_amdgcn_mfma_f32_16x16x32_bf16(af[m], bf[n], acc[m][n], 0, 0, 0);
    }
    // single barrier per K-step: (a) readers of buf cur done before it is
    // overwritten next iteration; (b) implicit vmcnt(0) completes prefetch.
    __syncthreads();
  }

  // epilogue: C/D layout col = lane&15, row = (lane>>4)*4 + reg
  const int orow = (lane >> 4) * 4;
  const int ocol = lane & 15;
  #pragma unroll
  for (int n = 0; n < 4; n++) {
    const int col = bn0 + wn0 + n*16 + ocol;
    const float bv = bias[col];
    #pragma unroll
    for (int m = 0; m < 4; m++) {
      #pragma unroll
      for (int r = 0; r < 4; r++) {
        float v = acc[m][n][r] + bv;
        if (epi == 1) v = silu_f(v);
        else if (epi == 2) v = softplus_f(v);
        C[(size_t)(bm0 + wm0 + m*16 + orow + r) * Nn + col] = v;
      }
    }
  }
}

__global__ __launch_bounds__(256) void gemm_bf16_k(
    const short* __restrict__ Ab, const short* __restrict__ Bt,
    const float* __restrict__ bias, float* __restrict__ C,
    int Nn, int K, int epi)
{
  __shared__ short As[2*128*64];
  __shared__ short Bs[2*128*64];
  int2 p = xcd_swz(gridDim.x);
  gemm_core(Ab, Bt, bias, C, Nn, K, p.y * 128, p.x * 128, epi, As, Bs);
}

// fused in_proj + gate: grid.x = 16 (x<8 -> x1/no-act, x>=8 -> z/silu)
__global__ __launch_bounds__(256) void gemm_ing_k(
    const short* __restrict__ ub,
    const short* __restrict__ Wti, const short* __restrict__ Wtg,
    const float* __restrict__ b_in, const float* __restrict__ bg,
    float* __restrict__ x1, float* __restrict__ z)
{
  __shared__ short As[2*128*64];
  __shared__ short Bs[2*128*64];
  int2 p = xcd_swz(gridDim.x);
  const int gate = p.x >> 3;
  gemm_core(ub, gate ? Wtg : Wti, gate ? bg : b_in, gate ? z : x1,
            DD, DD, p.y * 128, (p.x & 7) * 128, gate ? 1 : 0, As, Bs);
}

// ---------------------------------------------------------------------------
// Fused dt GEMM + B/C projections, 2-phase pipelined.
// grid (9, 32): x<8 -> dt tiles (softplus); x==8 -> 128x32 B/C tile via MFMA.
// ---------------------------------------------------------------------------
__global__ __launch_bounds__(256) void gemm_dtbc_k(
    const short* __restrict__ xb, const short* __restrict__ Wtd,
    const short* __restrict__ Wbct,
    const float* __restrict__ bdt, const float* __restrict__ bb,
    const float* __restrict__ bc,
    float* __restrict__ dt, float* __restrict__ Bm, float* __restrict__ Cm)
{
  __shared__ short As[2*128*64];
  __shared__ short Bs[2*128*64];
  int2 p = xcd_swz(gridDim.x);
  if (p.x < 8) {
    gemm_core(xb, Wtd, bdt, dt, DD, DD, p.y * 128, p.x * 128, 2, As, Bs);
    return;
  }
  // ---- B/C path: C'[128][32] = xb_tile @ Wbct^T, 2-phase ----
  const int tid  = threadIdx.x;
  const int lane = tid & 63;
  const int w    = tid >> 6;          // wave 0..3 -> 32-row band
  const int bm0  = p.y * 128;
  const int wm0  = w * 32;

  const int srow = tid >> 3;          // 0..31
  const int scol = (tid & 7) * 8;
  const short* gA = xb + (size_t)(bm0 + srow) * DD + scol;
  const short* gB = Wbct + (size_t)srow * DD + scol;   // 32 rows
  char* ldsA = (char*)As;
  char* ldsB = (char*)Bs;
  const int wuni = w * 1024;

  f32x4 acc[2][2];
  const f32x4 zz = {0.f, 0.f, 0.f, 0.f};
  #pragma unroll
  for (int m = 0; m < 2; m++)
    #pragma unroll
    for (int n = 0; n < 2; n++) acc[m][n] = zz;

  const int fr = lane & 15;
  const int ks = (lane >> 4) * 8;

  // prologue
  #pragma unroll
  for (int i = 0; i < 4; i++)
    gload16(gA + (size_t)(i * 32) * DD, ldsA + i * 4096 + wuni);
  gload16(gB, ldsB + wuni);
  __syncthreads();

  for (int t = 0; t < 16; ++t) {
    const int cur = t & 1;
    if (t + 1 < 16) {
      const int k1 = (t + 1) << 6;
      const int bo = (cur ^ 1) * 16384;
      #pragma unroll
      for (int i = 0; i < 4; i++)
        gload16(gA + (size_t)(i * 32) * DD + k1, ldsA + bo + i * 4096 + wuni);
      gload16(gB + k1, ldsB + bo + wuni);
    }
    const short* Ac = As + cur * 8192;
    const short* Bc = Bs + cur * 8192;
    #pragma unroll
    for (int s = 0; s < 2; s++) {
      bf16x8 af[2], bf[2];
      #pragma unroll
      for (int m = 0; m < 2; m++)
        af[m] = *(const bf16x8*)&Ac[(wm0 + m*16 + fr) * 64 + s*32 + ks];
      #pragma unroll
      for (int n = 0; n < 2; n++)
        bf[n] = *(const bf16x8*)&Bc[(n*16 + fr) * 64 + s*32 + ks];
      #pragma unroll
      for (int m = 0; m < 2; m++)
        #pragma unroll
        for (int n = 0; n < 2; n++)
          acc[m][n] = __builtin_amdgcn_mfma_f32_16x16x32_bf16(af[m], bf[n], acc[m][n], 0, 0, 0);
    }
    __syncthreads();
  }

  const int orow = (lane >> 4) * 4;
  const int ocol = lane & 15;
  const float bbv = bb[ocol];
  const float bcv = bc[ocol];
  #pragma unroll
  for (int m = 0; m < 2; m++) {
    #pragma unroll
    for (int r = 0; r < 4; r++) {
      int row = bm0 + wm0 + m*16 + orow + r;
      Bm[(size_t)row * NNs + ocol] = acc[m][0][r] + bbv;
      Cm[(size_t)row * NNs + ocol] = acc[m][1][r] + bcv;
    }
  }
}

// ---------------------------------------------------------------------------
// Depthwise conv3 (same over T) + silu. Writes fp32 x and bf16 xb.
// ---------------------------------------------------------------------------
__global__ __launch_bounds__(256) void conv_silu(
    const float* __restrict__ x1, const float* __restrict__ cw,
    const float* __restrict__ cb, float* __restrict__ x,
    short* __restrict__ xb)
{
  int idx = blockIdx.x * 256 + threadIdx.x;       // over MM*DD/4
  int d4 = idx & (DD/4 - 1);
  int bt = idx >> 8;                              // DD/4 == 256
  int t  = bt & (TT - 1);
  const float4* b4 = (const float4*)x1;
  size_t ri = (size_t)bt * (DD/4) + d4;
  float4 zz = make_float4(0.f, 0.f, 0.f, 0.f);
  float4 vc = b4[ri];
  float4 vm = (t > 0)      ? b4[ri - DD/4] : zz;
  float4 vp = (t < TT - 1) ? b4[ri + DD/4] : zz;
  float rm[4] = {vm.x, vm.y, vm.z, vm.w};
  float rc[4] = {vc.x, vc.y, vc.z, vc.w};
  float rp[4] = {vp.x, vp.y, vp.z, vp.w};
  float o[4];
  #pragma unroll
  for (int j = 0; j < 4; j++) {
    int d = d4*4 + j;
    float v = rm[j]*cw[d*3+0] + rc[j]*cw[d*3+1] + rp[j]*cw[d*3+2] + cb[d];
    o[j] = silu_f(v);
  }
  ((float4*)x)[ri] = make_float4(o[0], o[1], o[2], o[3]);
  ((uint2*)xb)[ri] = make_uint2(pk2(o[0], o[1]), pk2(o[2], o[3]));
}

// ---------------------------------------------------------------------------
// Selective scan, 3-phase chunked (16 chunks of 64)
// ---------------------------------------------------------------------------
__global__ __launch_bounds__(256) void scan_local(
    const float* __restrict__ dt, const float* __restrict__ x,
    const float* __restrict__ Bm, const float* __restrict__ A,
    float* __restrict__ P, float* __restrict__ S)
{
  __shared__ float Bs[CHUNK*NNs];
  int bid = blockIdx.x;
  int dblk = bid & 3;
  int c = (bid >> 2) & 15;
  int b = bid >> 6;
  int d = dblk*256 + threadIdx.x;
  int t0 = c * CHUNK;
  for (int i = threadIdx.x; i < CHUNK*NNs; i += 256)
    Bs[i] = Bm[(size_t)(b*TT + t0)*NNs + i];
  float a[NNs];
  #pragma unroll
  for (int n = 0; n < NNs; n++) a[n] = A[d*NNs + n];
  __syncthreads();
  float h[NNs], p[NNs];
  #pragma unroll
  for (int n = 0; n < NNs; n++) { h[n] = 0.f; p[n] = 1.f; }
  size_t base = (size_t)(b*TT + t0)*DD + d;
  for (int tt = 0; tt < CHUNK; tt++) {
    float dtv = dt[base + (size_t)tt*DD];
    float xv  = x [base + (size_t)tt*DD];
    float dx = dtv * xv;
    #pragma unroll
    for (int n = 0; n < NNs; n++) {
      float e = __expf(dtv * a[n]);
      h[n] = fmaf(e, h[n], dx * Bs[tt*NNs + n]);
      p[n] *= e;
    }
  }
  size_t o = ((size_t)((b*NCHUNK + c)*DD + d)) * NNs;
  #pragma unroll
  for (int n = 0; n < NNs; n += 4) {
    *(float4*)&P[o+n] = make_float4(p[n], p[n+1], p[n+2], p[n+3]);
    *(float4*)&S[o+n] = make_float4(h[n], h[n+1], h[n+2], h[n+3]);
  }
}

__global__ __launch_bounds__(256) void scan_combine(
    const float* __restrict__ P, const float* __restrict__ S,
    float* __restrict__ H0)
{
  int g = blockIdx.x*256 + threadIdx.x;   // B*DD*NNs = 65536
  int n = g & 15; int d = (g >> 4) & 1023; int b = g >> 14;
  float h = 0.f;
  for (int c = 0; c < NCHUNK; c++) {
    size_t idx = ((size_t)((b*NCHUNK + c)*DD + d)) * NNs + n;
    H0[idx] = h;
    h = fmaf(P[idx], h, S[idx]);
  }
}

// Phase 3: replay with correct h0; y = <h,C>; fuse gate; write bf16 xsb
__global__ __launch_bounds__(256) void scan_y(
    const float* __restrict__ dt, const float* __restrict__ x,
    const float* __restrict__ Bm, const float* __restrict__ Cm,
    const float* __restrict__ A,  const float* __restrict__ H0,
    const float* __restrict__ z,  short* __restrict__ xsb)
{
  __shared__ float Bs[CHUNK*NNs];
  __shared__ float Cs[CHUNK*NNs];
  int bid = blockIdx.x;
  int dblk = bid & 3;
  int c = (bid >> 2) & 15;
  int b = bid >> 6;
  int d = dblk*256 + threadIdx.x;
  int t0 = c * CHUNK;
  for (int i = threadIdx.x; i < CHUNK*NNs; i += 256) {
    Bs[i] = Bm[(size_t)(b*TT + t0)*NNs + i];
    Cs[i] = Cm[(size_t)(b*TT + t0)*NNs + i];
  }
  float a[NNs];
  #pragma unroll
  for (int n = 0; n < NNs; n++) a[n] = A[d*NNs + n];
  size_t ho = ((size_t)((b*NCHUNK + c)*DD + d)) * NNs;
  float h[NNs];
  #pragma unroll
  for (int n = 0; n < NNs; n += 4) {
    float4 h4 = *(const float4*)&H0[ho+n];
    h[n] = h4.x; h[n+1] = h4.y; h[n+2] = h4.z; h[n+3] = h4.w;
  }
  __syncthreads();
  size_t base = (size_t)(b*TT + t0)*DD + d;
  for (int tt = 0; tt < CHUNK; tt++) {
    float dtv = dt[base + (size_t)tt*DD];
    float xv  = x [base + (size_t)tt*DD];
    float dx = dtv * xv;
    float y = 0.f;
    #pragma unroll
    for (int n = 0; n < NNs; n++) {
      float e = __expf(dtv * a[n]);
      h[n] = fmaf(e, h[n], dx * Bs[tt*NNs + n]);
      y = fmaf(h[n], Cs[tt*NNs + n], y);
    }
    size_t gi = base + (size_t)tt*DD;
    xsb[gi] = (short)f2bf(y * z[gi]);
  }
}

// ---------------------------------------------------------------------------
extern "C" void kernel_launch(void* const* d_in, const int* in_sizes, int n_in,
                              void* d_out, int out_size, void* d_ws, size_t ws_size,
                              hipStream_t stream)
{
  const float* u     = (const float*)d_in[0];
  const float* Win   = (const float*)d_in[1];
  const float* b_in  = (const float*)d_in[2];
  const float* Wg    = (const float*)d_in[3];
  const float* bg    = (const float*)d_in[4];
  const float* Wout  = (const float*)d_in[5];
  const float* bout  = (const float*)d_in[6];
  const float* convw = (const float*)d_in[7];
  const float* convb = (const float*)d_in[8];
  const float* A     = (const float*)d_in[9];
  const float* Wb    = (const float*)d_in[10];
  const float* bb    = (const float*)d_in[11];
  const float* Wc    = (const float*)d_in[12];
  const float* bc    = (const float*)d_in[13];
  const float* Wdt   = (const float*)d_in[14];
  const float* bdt   = (const float*)d_in[15];
  float* out = (float*)d_out;

  // workspace layout (~88.6 MB)
  float* ws = (float*)d_ws;
  float* x1 = ws;                         // [M,D] f32 (later reused for P/S/H0)
  float* z  = x1 + MMDD;                  // [M,D] f32
  float* x  = z  + MMDD;                  // [M,D] f32
  float* dt = x  + MMDD;                  // [M,D] f32
  float* Bm = dt + MMDD;                  // [M,N]
  float* Cm = Bm + (size_t)MM*NNs;        // [M,N]
  short* ub  = (short*)(Cm + (size_t)MM*NNs);  // [M,D] bf16
  short* xb  = ub  + MMDD;                // [M,D] bf16
  short* Wti = xb  + MMDD;                // [D,D] bf16 transposed
  short* Wtg = Wti + (size_t)DD*DD;
  short* Wtd = Wtg + (size_t)DD*DD;
  short* Wto = Wtd + (size_t)DD*DD;
  short* Wbct = Wto + (size_t)DD*DD;      // [32,D] bf16 (Wb^T | Wc^T)
  float* P  = x1;                         // reuse x1 region after conv
  float* S  = P + (size_t)BB*NCHUNK*DD*NNs;
  float* H0 = S + (size_t)BB*NCHUNK*DD*NNs;
  short* xsb = ub;                        // reuse ub region after in/gate GEMM

  // 0) weight prep (one z-batched dispatch + tiny B/C transpose) and u->bf16
  wconv_t4<<<dim3(DD/32, DD/32, 4), 256, 0, stream>>>(
      Win, Wg, Wdt, Wout, Wti, Wtg, Wtd, Wto);
  wbc_t<<<(32*DD)/256, 256, 0, stream>>>(Wb, Wc, Wbct);
  to_bf16<<<(MMDD/8)/256, 256, 0, stream>>>(u, ub);

  // 1) fused in_proj (x1) + gate (z, silu)
  gemm_ing_k<<<dim3(16, MM/128), 256, 0, stream>>>(ub, Wti, Wtg, b_in, bg, x1, z);
  // 2) depthwise conv + silu -> x (f32) + xb (bf16)
  conv_silu<<<(MMDD/4)/256, 256, 0, stream>>>(x1, convw, convb, x, xb);
  // 3) dt = softplus(x@Wdt + bdt)  AND  Bm/Cm = x@[Wb|Wc] (MFMA, fused)
  gemm_dtbc_k<<<dim3(9, MM/128), 256, 0, stream>>>(
      xb, Wtd, Wbct, bdt, bb, bc, dt, Bm, Cm);
  // 4-6) chunked selective scan (+ gate fused in phase 3, writes bf16)
  scan_local  <<<BB*NCHUNK*(DD/256), 256, 0, stream>>>(dt, x, Bm, A, P, S);
  scan_combine<<<(BB*DD*NNs)/256,    256, 0, stream>>>(P, S, H0);
  scan_y      <<<BB*NCHUNK*(DD/256), 256, 0, stream>>>(dt, x, Bm, Cm, A, H0, z, xsb);
  // 7) out = xs @ Wout + bout
  gemm_bf16_k<<<dim3(8, MM/128), 256, 0, stream>>>(xsb, Wto, bout, out, DD, DD, 0);
}

// Round 8
// 307.982 us; speedup vs baseline: 2.5883x; 1.0440x over previous
//
#include <hip/hip_runtime.h>
#include <hip/hip_bf16.h>
#include <math.h>

// Problem constants (B,T,D,N from the reference)
#define BB 4
#define TT 1024
#define DD 1024
#define NNs 16
#define MM (BB*TT)          // 4096 rows
#define MMDD ((size_t)MM*DD)
#define CHUNK 64
#define NCHUNK (TT/CHUNK)   // 16

typedef short bf16x8 __attribute__((ext_vector_type(8)));
typedef float f32x4  __attribute__((ext_vector_type(4)));

__device__ __forceinline__ float silu_f(float v)     { return v / (1.f + __expf(-v)); }
__device__ __forceinline__ float softplus_f(float v) { return fmaxf(v, 0.f) + log1pf(__expf(-fabsf(v))); }

// fp32 -> bf16 (RNE) as raw bits
__device__ __forceinline__ unsigned short f2bf(float f) {
  unsigned u = __builtin_bit_cast(unsigned, f);
  u += 0x7fffu + ((u >> 16) & 1u);
  return (unsigned short)(u >> 16);
}
__device__ __forceinline__ unsigned pk2(float a, float b) {
  return (unsigned)f2bf(a) | ((unsigned)f2bf(b) << 16);
}

// async global->LDS, 16B per lane; lds ptr must be wave-uniform
__device__ __forceinline__ void gload16(const void* g, void* l) {
  __builtin_amdgcn_global_load_lds(
      (const __attribute__((address_space(1))) unsigned*)g,
      (__attribute__((address_space(3))) unsigned*)l, 16, 0, 0);
}

// T1: bijective chunked XCD swizzle (m204).
__device__ __forceinline__ int2 xcd_swz(int gx) {
  int nwg  = gx * (int)gridDim.y;
  int orig = (int)blockIdx.y * gx + (int)blockIdx.x;
  int q = nwg >> 3, r = nwg & 7;
  int xcd = orig & 7, i = orig >> 3;
  int wg = (xcd < r ? xcd * (q + 1) : r * (q + 1) + (xcd - r) * q) + i;
  return make_int2(wg % gx, wg / gx);
}

// ---------------------------------------------------------------------------
// Weight convert+transpose x4: W[K][N] f32 -> Wt[N][K] bf16 (K=N=DD), z-batched
// ---------------------------------------------------------------------------
__global__ __launch_bounds__(256) void wconv_t4(
    const float* __restrict__ W0, const float* __restrict__ W1,
    const float* __restrict__ W2, const float* __restrict__ W3,
    short* __restrict__ o0, short* __restrict__ o1,
    short* __restrict__ o2, short* __restrict__ o3)
{
  const float* W; short* Wt;
  switch (blockIdx.z) {
    case 0:  W = W0; Wt = o0; break;
    case 1:  W = W1; Wt = o1; break;
    case 2:  W = W2; Wt = o2; break;
    default: W = W3; Wt = o3; break;
  }
  __shared__ float t[32][33];
  int n0 = blockIdx.x * 32, k0 = blockIdx.y * 32;
  int r  = threadIdx.x >> 3;
  int c4 = (threadIdx.x & 7) * 4;
  float4 v = *(const float4*)(W + (size_t)(k0 + r) * DD + n0 + c4);
  t[r][c4+0] = v.x; t[r][c4+1] = v.y; t[r][c4+2] = v.z; t[r][c4+3] = v.w;
  __syncthreads();
  short q0 = (short)f2bf(t[c4+0][r]);
  short q1 = (short)f2bf(t[c4+1][r]);
  short q2 = (short)f2bf(t[c4+2][r]);
  short q3 = (short)f2bf(t[c4+3][r]);
  *(short4*)(Wt + (size_t)(n0 + r) * DD + k0 + c4) = make_short4(q0, q1, q2, q3);
}

// Wb[D][16], Wc[D][16] f32 -> Wbct[32][D] bf16 (rows 0-15 = Wb^T, 16-31 = Wc^T)
__global__ __launch_bounds__(256) void wbc_t(
    const float* __restrict__ Wb, const float* __restrict__ Wc,
    short* __restrict__ Wbct)
{
  int idx = blockIdx.x * 256 + threadIdx.x;  // 32*1024 = 32768
  int k = idx & (DD - 1);
  int n = idx >> 10;
  const float* W = (n < 16) ? Wb : Wc;
  Wbct[(size_t)n * DD + k] = (short)f2bf(W[(size_t)k * NNs + (n & 15)]);
}

// fp32 -> bf16 bulk convert (8 elems/thread)
__global__ __launch_bounds__(256) void to_bf16(
    const float* __restrict__ in, short* __restrict__ out)
{
  size_t i = (size_t)(blockIdx.x * 256 + threadIdx.x) * 8;
  float4 a = *(const float4*)(in + i);
  float4 b = *(const float4*)(in + i + 4);
  *(uint4*)(out + i) = make_uint4(pk2(a.x,a.y), pk2(a.z,a.w),
                                  pk2(b.x,b.y), pk2(b.z,b.w));
}

// ---------------------------------------------------------------------------
// bf16 MFMA GEMM core, 2-phase double-buffered + T2 XOR LDS swizzle.
// LDS tile is [128][64] bf16 (128B rows). Without swizzle, frag reads
// (16 lanes, 16 different rows, same 16B col) are a 16-way bank conflict.
// rule #21: global_load_lds writes linearly -> swizzle BOTH the global
// source column (scol ^= (srow&7)<<3 elems) and the read column
// (cs = ((s<<5)|ks) ^ ((fr&7)<<3)); LDS dest stays linear.
// epi: 0=none, 1=silu, 2=softplus
// ---------------------------------------------------------------------------
__device__ __forceinline__ void gemm_core(
    const short* __restrict__ Ab, const short* __restrict__ Bt,
    const float* __restrict__ bias, float* __restrict__ C,
    int Nn, int K, int bm0, int bn0, int epi,
    short* As, short* Bs)
{
  const int tid  = threadIdx.x;
  const int lane = tid & 63;
  const int w    = tid >> 6;          // wave 0..3
  const int wm0  = (w >> 1) * 64;
  const int wn0  = (w & 1) * 64;

  const int srow = tid >> 3;          // 0..31 (staging row)
  const int scol = ((tid & 7) ^ ((tid >> 3) & 7)) << 3;  // pre-swizzled src col

  const short* gA = Ab + (size_t)(bm0 + srow) * K + scol;
  const short* gB = Bt + (size_t)(bn0 + srow) * K + scol;
  char* ldsA = (char*)As;
  char* ldsB = (char*)Bs;
  const int wuni = w * 1024;          // wave-uniform LDS byte offset

  f32x4 acc[4][4];
  const f32x4 zz = {0.f, 0.f, 0.f, 0.f};
  #pragma unroll
  for (int m = 0; m < 4; m++)
    #pragma unroll
    for (int n = 0; n < 4; n++) acc[m][n] = zz;

  const int fr  = lane & 15;          // frag row (A) / col (B)
  const int ks  = (lane >> 4) << 3;   // frag k-offset (elems) within 32-slice
  const int swz = (fr & 7) << 3;      // T2 read-side XOR (elems)

  const int NT = K >> 6;

  // prologue: stage tile 0 into buf 0
  #pragma unroll
  for (int i = 0; i < 4; i++) {
    gload16(gA + (size_t)(i * 32) * K, ldsA + i * 4096 + wuni);
    gload16(gB + (size_t)(i * 32) * K, ldsB + i * 4096 + wuni);
  }
  __syncthreads();

  for (int t = 0; t < NT; ++t) {
    const int cur = t & 1;
    if (t + 1 < NT) {                 // prefetch next tile into other buf
      const int k1 = (t + 1) << 6;
      const int bo = (cur ^ 1) * 16384;
      #pragma unroll
      for (int i = 0; i < 4; i++) {
        gload16(gA + (size_t)(i * 32) * K + k1, ldsA + bo + i * 4096 + wuni);
        gload16(gB + (size_t)(i * 32) * K + k1, ldsB + bo + i * 4096 + wuni);
      }
    }
    const short* Ac = As + cur * 8192;
    const short* Bc = Bs + cur * 8192;
    #pragma unroll
    for (int s = 0; s < 2; s++) {
      const int cs = ((s << 5) | ks) ^ swz;
      bf16x8 af[4], bf[4];
      #pragma unroll
      for (int m = 0; m < 4; m++)
        af[m] = *(const bf16x8*)&Ac[(wm0 + m*16 + fr) * 64 + cs];
      #pragma unroll
      for (int n = 0; n < 4; n++)
        bf[n] = *(const bf16x8*)&Bc[(wn0 + n*16 + fr) * 64 + cs];
      #pragma unroll
      for (int m = 0; m < 4; m++)
        #pragma unroll
        for (int n = 0; n < 4; n++)
          acc[m][n] = __builtin_amdgcn_mfma_f32_16x16x32_bf16(af[m], bf[n], acc[m][n], 0, 0, 0);
    }
    __syncthreads();
  }

  // epilogue: C/D layout col = lane&15, row = (lane>>4)*4 + reg
  const int orow = (lane >> 4) * 4;
  const int ocol = lane & 15;
  #pragma unroll
  for (int n = 0; n < 4; n++) {
    const int col = bn0 + wn0 + n*16 + ocol;
    const float bv = bias[col];
    #pragma unroll
    for (int m = 0; m < 4; m++) {
      #pragma unroll
      for (int r = 0; r < 4; r++) {
        float v = acc[m][n][r] + bv;
        if (epi == 1) v = silu_f(v);
        else if (epi == 2) v = softplus_f(v);
        C[(size_t)(bm0 + wm0 + m*16 + orow + r) * Nn + col] = v;
      }
    }
  }
}

__global__ __launch_bounds__(256) void gemm_bf16_k(
    const short* __restrict__ Ab, const short* __restrict__ Bt,
    const float* __restrict__ bias, float* __restrict__ C,
    int Nn, int K, int epi)
{
  __shared__ short As[2*128*64];
  __shared__ short Bs[2*128*64];
  int2 p = xcd_swz(gridDim.x);
  gemm_core(Ab, Bt, bias, C, Nn, K, p.y * 128, p.x * 128, epi, As, Bs);
}

// fused in_proj + gate: grid.x = 16 (x<8 -> x1/no-act, x>=8 -> z/silu)
__global__ __launch_bounds__(256) void gemm_ing_k(
    const short* __restrict__ ub,
    const short* __restrict__ Wti, const short* __restrict__ Wtg,
    const float* __restrict__ b_in, const float* __restrict__ bg,
    float* __restrict__ x1, float* __restrict__ z)
{
  __shared__ short As[2*128*64];
  __shared__ short Bs[2*128*64];
  int2 p = xcd_swz(gridDim.x);
  const int gate = p.x >> 3;
  gemm_core(ub, gate ? Wtg : Wti, gate ? bg : b_in, gate ? z : x1,
            DD, DD, p.y * 128, (p.x & 7) * 128, gate ? 1 : 0, As, Bs);
}

// ---------------------------------------------------------------------------
// Fused dt GEMM + B/C projections, uniform 256-block grid (8,32).
// Block (x,y): 128x128 dt tile AND B/C rows [y*128+x*16, +16) x 32 cols.
// BC A-frags come from the A-LDS tile already staged; Wbct tile [32][64]
// staged per K-step (4KB, one gload16 per wave). Waves 0/1 each do one
// extra MFMA per s-pass (wave0 -> Bm, wave1 -> Cm).
// ---------------------------------------------------------------------------
__global__ __launch_bounds__(256) void gemm_dtbc_k(
    const short* __restrict__ xb, const short* __restrict__ Wtd,
    const short* __restrict__ Wbct,
    const float* __restrict__ bdt, const float* __restrict__ bb,
    const float* __restrict__ bc,
    float* __restrict__ dt, float* __restrict__ Bm, float* __restrict__ Cm)
{
  __shared__ short As[2*128*64];
  __shared__ short Bs[2*128*64];
  __shared__ short Cs[2*32*64];
  int2 p = xcd_swz(gridDim.x);
  const int bx = p.x;
  const int bm0 = p.y * 128;
  const int bn0 = bx * 128;

  const int tid  = threadIdx.x;
  const int lane = tid & 63;
  const int w    = tid >> 6;
  const int wm0  = (w >> 1) * 64;
  const int wn0  = (w & 1) * 64;

  const int srow = tid >> 3;
  const int scol = ((tid & 7) ^ ((tid >> 3) & 7)) << 3;

  const short* gA = xb   + (size_t)(bm0 + srow) * DD + scol;
  const short* gB = Wtd  + (size_t)(bn0 + srow) * DD + scol;
  const short* gC = Wbct + (size_t)srow * DD + scol;
  char* ldsA = (char*)As;
  char* ldsB = (char*)Bs;
  char* ldsC = (char*)Cs;
  const int wuni = w * 1024;

  f32x4 acc[4][4];
  const f32x4 zz = {0.f, 0.f, 0.f, 0.f};
  #pragma unroll
  for (int m = 0; m < 4; m++)
    #pragma unroll
    for (int n = 0; n < 4; n++) acc[m][n] = zz;
  f32x4 accbc = zz;

  const int fr  = lane & 15;
  const int ks  = (lane >> 4) << 3;
  const int swz = (fr & 7) << 3;

  // prologue
  #pragma unroll
  for (int i = 0; i < 4; i++) {
    gload16(gA + (size_t)(i * 32) * DD, ldsA + i * 4096 + wuni);
    gload16(gB + (size_t)(i * 32) * DD, ldsB + i * 4096 + wuni);
  }
  gload16(gC, ldsC + wuni);
  __syncthreads();

  for (int t = 0; t < 16; ++t) {
    const int cur = t & 1;
    if (t + 1 < 16) {
      const int k1 = (t + 1) << 6;
      const int bo = (cur ^ 1) * 16384;
      #pragma unroll
      for (int i = 0; i < 4; i++) {
        gload16(gA + (size_t)(i * 32) * DD + k1, ldsA + bo + i * 4096 + wuni);
        gload16(gB + (size_t)(i * 32) * DD + k1, ldsB + bo + i * 4096 + wuni);
      }
      gload16(gC + k1, ldsC + (cur ^ 1) * 4096 + wuni);
    }
    const short* Ac = As + cur * 8192;
    const short* Bc = Bs + cur * 8192;
    const short* Cc = Cs + cur * 2048;
    #pragma unroll
    for (int s = 0; s < 2; s++) {
      const int cs = ((s << 5) | ks) ^ swz;
      bf16x8 af[4], bf[4];
      #pragma unroll
      for (int m = 0; m < 4; m++)
        af[m] = *(const bf16x8*)&Ac[(wm0 + m*16 + fr) * 64 + cs];
      #pragma unroll
      for (int n = 0; n < 4; n++)
        bf[n] = *(const bf16x8*)&Bc[(wn0 + n*16 + fr) * 64 + cs];
      #pragma unroll
      for (int m = 0; m < 4; m++)
        #pragma unroll
        for (int n = 0; n < 4; n++)
          acc[m][n] = __builtin_amdgcn_mfma_f32_16x16x32_bf16(af[m], bf[n], acc[m][n], 0, 0, 0);
      if (w < 2) {
        bf16x8 abc = *(const bf16x8*)&Ac[(bx*16 + fr) * 64 + cs];
        bf16x8 bbc = *(const bf16x8*)&Cc[((w << 4) + fr) * 64 + cs];
        accbc = __builtin_amdgcn_mfma_f32_16x16x32_bf16(abc, bbc, accbc, 0, 0, 0);
      }
    }
    __syncthreads();
  }

  const int orow = (lane >> 4) * 4;
  const int ocol = lane & 15;
  #pragma unroll
  for (int n = 0; n < 4; n++) {
    const int col = bn0 + wn0 + n*16 + ocol;
    const float bv = bdt[col];
    #pragma unroll
    for (int m = 0; m < 4; m++) {
      #pragma unroll
      for (int r = 0; r < 4; r++) {
        float v = acc[m][n][r] + bv;
        dt[(size_t)(bm0 + wm0 + m*16 + orow + r) * DD + col] = softplus_f(v);
      }
    }
  }
  if (w < 2) {
    const float bv = (w == 0 ? bb : bc)[ocol];
    float* dst = (w == 0) ? Bm : Cm;
    #pragma unroll
    for (int r = 0; r < 4; r++) {
      int row = bm0 + bx*16 + orow + r;
      dst[(size_t)row * NNs + ocol] = accbc[r] + bv;
    }
  }
}

// ---------------------------------------------------------------------------
// Depthwise conv3 (same over T) + silu. Writes fp32 x and bf16 xb.
// ---------------------------------------------------------------------------
__global__ __launch_bounds__(256) void conv_silu(
    const float* __restrict__ x1, const float* __restrict__ cw,
    const float* __restrict__ cb, float* __restrict__ x,
    short* __restrict__ xb)
{
  int idx = blockIdx.x * 256 + threadIdx.x;       // over MM*DD/4
  int d4 = idx & (DD/4 - 1);
  int bt = idx >> 8;                              // DD/4 == 256
  int t  = bt & (TT - 1);
  const float4* b4 = (const float4*)x1;
  size_t ri = (size_t)bt * (DD/4) + d4;
  float4 zz = make_float4(0.f, 0.f, 0.f, 0.f);
  float4 vc = b4[ri];
  float4 vm = (t > 0)      ? b4[ri - DD/4] : zz;
  float4 vp = (t < TT - 1) ? b4[ri + DD/4] : zz;
  float rm[4] = {vm.x, vm.y, vm.z, vm.w};
  float rc[4] = {vc.x, vc.y, vc.z, vc.w};
  float rp[4] = {vp.x, vp.y, vp.z, vp.w};
  float o[4];
  #pragma unroll
  for (int j = 0; j < 4; j++) {
    int d = d4*4 + j;
    float v = rm[j]*cw[d*3+0] + rc[j]*cw[d*3+1] + rp[j]*cw[d*3+2] + cb[d];
    o[j] = silu_f(v);
  }
  ((float4*)x)[ri] = make_float4(o[0], o[1], o[2], o[3]);
  ((uint2*)xb)[ri] = make_uint2(pk2(o[0], o[1]), pk2(o[2], o[3]));
}

// ---------------------------------------------------------------------------
// Selective scan, 3-phase chunked (16 chunks of 64)
// ---------------------------------------------------------------------------
__global__ __launch_bounds__(256) void scan_local(
    const float* __restrict__ dt, const float* __restrict__ x,
    const float* __restrict__ Bm, const float* __restrict__ A,
    float* __restrict__ P, float* __restrict__ S)
{
  __shared__ float Bs[CHUNK*NNs];
  int bid = blockIdx.x;
  int dblk = bid & 3;
  int c = (bid >> 2) & 15;
  int b = bid >> 6;
  int d = dblk*256 + threadIdx.x;
  int t0 = c * CHUNK;
  for (int i = threadIdx.x; i < CHUNK*NNs; i += 256)
    Bs[i] = Bm[(size_t)(b*TT + t0)*NNs + i];
  float a[NNs];
  #pragma unroll
  for (int n = 0; n < NNs; n++) a[n] = A[d*NNs + n];
  __syncthreads();
  float h[NNs], p[NNs];
  #pragma unroll
  for (int n = 0; n < NNs; n++) { h[n] = 0.f; p[n] = 1.f; }
  size_t base = (size_t)(b*TT + t0)*DD + d;
  for (int tt = 0; tt < CHUNK; tt++) {
    float dtv = dt[base + (size_t)tt*DD];
    float xv  = x [base + (size_t)tt*DD];
    float dx = dtv * xv;
    #pragma unroll
    for (int n = 0; n < NNs; n++) {
      float e = __expf(dtv * a[n]);
      h[n] = fmaf(e, h[n], dx * Bs[tt*NNs + n]);
      p[n] *= e;
    }
  }
  size_t o = ((size_t)((b*NCHUNK + c)*DD + d)) * NNs;
  #pragma unroll
  for (int n = 0; n < NNs; n += 4) {
    *(float4*)&P[o+n] = make_float4(p[n], p[n+1], p[n+2], p[n+3]);
    *(float4*)&S[o+n] = make_float4(h[n], h[n+1], h[n+2], h[n+3]);
  }
}

__global__ __launch_bounds__(256) void scan_combine(
    const float* __restrict__ P, const float* __restrict__ S,
    float* __restrict__ H0)
{
  int g = blockIdx.x*256 + threadIdx.x;   // B*DD*NNs = 65536
  int n = g & 15; int d = (g >> 4) & 1023; int b = g >> 14;
  float h = 0.f;
  for (int c = 0; c < NCHUNK; c++) {
    size_t idx = ((size_t)((b*NCHUNK + c)*DD + d)) * NNs + n;
    H0[idx] = h;
    h = fmaf(P[idx], h, S[idx]);
  }
}

// Phase 3: replay with correct h0; y = <h,C>; fuse gate; write bf16 xsb
__global__ __launch_bounds__(256) void scan_y(
    const float* __restrict__ dt, const float* __restrict__ x,
    const float* __restrict__ Bm, const float* __restrict__ Cm,
    const float* __restrict__ A,  const float* __restrict__ H0,
    const float* __restrict__ z,  short* __restrict__ xsb)
{
  __shared__ float Bs[CHUNK*NNs];
  __shared__ float Cs[CHUNK*NNs];
  int bid = blockIdx.x;
  int dblk = bid & 3;
  int c = (bid >> 2) & 15;
  int b = bid >> 6;
  int d = dblk*256 + threadIdx.x;
  int t0 = c * CHUNK;
  for (int i = threadIdx.x; i < CHUNK*NNs; i += 256) {
    Bs[i] = Bm[(size_t)(b*TT + t0)*NNs + i];
    Cs[i] = Cm[(size_t)(b*TT + t0)*NNs + i];
  }
  float a[NNs];
  #pragma unroll
  for (int n = 0; n < NNs; n++) a[n] = A[d*NNs + n];
  size_t ho = ((size_t)((b*NCHUNK + c)*DD + d)) * NNs;
  float h[NNs];
  #pragma unroll
  for (int n = 0; n < NNs; n += 4) {
    float4 h4 = *(const float4*)&H0[ho+n];
    h[n] = h4.x; h[n+1] = h4.y; h[n+2] = h4.z; h[n+3] = h4.w;
  }
  __syncthreads();
  size_t base = (size_t)(b*TT + t0)*DD + d;
  for (int tt = 0; tt < CHUNK; tt++) {
    float dtv = dt[base + (size_t)tt*DD];
    float xv  = x [base + (size_t)tt*DD];
    float dx = dtv * xv;
    float y = 0.f;
    #pragma unroll
    for (int n = 0; n < NNs; n++) {
      float e = __expf(dtv * a[n]);
      h[n] = fmaf(e, h[n], dx * Bs[tt*NNs + n]);
      y = fmaf(h[n], Cs[tt*NNs + n], y);
    }
    size_t gi = base + (size_t)tt*DD;
    xsb[gi] = (short)f2bf(y * z[gi]);
  }
}

// ---------------------------------------------------------------------------
extern "C" void kernel_launch(void* const* d_in, const int* in_sizes, int n_in,
                              void* d_out, int out_size, void* d_ws, size_t ws_size,
                              hipStream_t stream)
{
  const float* u     = (const float*)d_in[0];
  const float* Win   = (const float*)d_in[1];
  const float* b_in  = (const float*)d_in[2];
  const float* Wg    = (const float*)d_in[3];
  const float* bg    = (const float*)d_in[4];
  const float* Wout  = (const float*)d_in[5];
  const float* bout  = (const float*)d_in[6];
  const float* convw = (const float*)d_in[7];
  const float* convb = (const float*)d_in[8];
  const float* A     = (const float*)d_in[9];
  const float* Wb    = (const float*)d_in[10];
  const float* bb    = (const float*)d_in[11];
  const float* Wc    = (const float*)d_in[12];
  const float* bc    = (const float*)d_in[13];
  const float* Wdt   = (const float*)d_in[14];
  const float* bdt   = (const float*)d_in[15];
  float* out = (float*)d_out;

  // workspace layout (~88.6 MB)
  float* ws = (float*)d_ws;
  float* x1 = ws;                         // [M,D] f32 (later reused for P/S/H0)
  float* z  = x1 + MMDD;                  // [M,D] f32
  float* x  = z  + MMDD;                  // [M,D] f32
  float* dt = x  + MMDD;                  // [M,D] f32
  float* Bm = dt + MMDD;                  // [M,N]
  float* Cm = Bm + (size_t)MM*NNs;        // [M,N]
  short* ub  = (short*)(Cm + (size_t)MM*NNs);  // [M,D] bf16
  short* xb  = ub  + MMDD;                // [M,D] bf16
  short* Wti = xb  + MMDD;                // [D,D] bf16 transposed
  short* Wtg = Wti + (size_t)DD*DD;
  short* Wtd = Wtg + (size_t)DD*DD;
  short* Wto = Wtd + (size_t)DD*DD;
  short* Wbct = Wto + (size_t)DD*DD;      // [32,D] bf16 (Wb^T | Wc^T)
  float* P  = x1;                         // reuse x1 region after conv
  float* S  = P + (size_t)BB*NCHUNK*DD*NNs;
  float* H0 = S + (size_t)BB*NCHUNK*DD*NNs;
  short* xsb = ub;                        // reuse ub region after in/gate GEMM

  // 0) weight prep (one z-batched dispatch + tiny B/C transpose) and u->bf16
  wconv_t4<<<dim3(DD/32, DD/32, 4), 256, 0, stream>>>(
      Win, Wg, Wdt, Wout, Wti, Wtg, Wtd, Wto);
  wbc_t<<<(32*DD)/256, 256, 0, stream>>>(Wb, Wc, Wbct);
  to_bf16<<<(MMDD/8)/256, 256, 0, stream>>>(u, ub);

  // 1) fused in_proj (x1) + gate (z, silu)  [512 blocks = 2 exact rounds]
  gemm_ing_k<<<dim3(16, MM/128), 256, 0, stream>>>(ub, Wti, Wtg, b_in, bg, x1, z);
  // 2) depthwise conv + silu -> x (f32) + xb (bf16)
  conv_silu<<<(MMDD/4)/256, 256, 0, stream>>>(x1, convw, convb, x, xb);
  // 3) dt = softplus(x@Wdt + bdt) AND Bm/Cm, uniform 256-block grid
  gemm_dtbc_k<<<dim3(8, MM/128), 256, 0, stream>>>(
      xb, Wtd, Wbct, bdt, bb, bc, dt, Bm, Cm);
  // 4-6) chunked selective scan (+ gate fused in phase 3, writes bf16)
  scan_local  <<<BB*NCHUNK*(DD/256), 256, 0, stream>>>(dt, x, Bm, A, P, S);
  scan_combine<<<(BB*DD*NNs)/256,    256, 0, stream>>>(P, S, H0);
  scan_y      <<<BB*NCHUNK*(DD/256), 256, 0, stream>>>(dt, x, Bm, Cm, A, H0, z, xsb);
  // 7) out = xs @ Wout + bout  [256 blocks = 1 exact round]
  gemm_bf16_k<<<dim3(8, MM/128), 256, 0, stream>>>(xsb, Wto, bout, out, DD, DD, 0);
}